// Round 1
// baseline (3015.630 us; speedup 1.0000x reference)
//
#include <hip/hip_runtime.h>
#include <cstdint>
#include <cstddef>

#define NN 100000
#define D 128
#define NE 800000
#define BN_EPS 1e-5f

// ---------------------------------------------------------------------------
// result = (1 + eps[0][d]) * x0
__global__ __launch_bounds__(256) void k_init(const float* __restrict__ x0,
                                              const float* __restrict__ eps,
                                              float* __restrict__ result) {
  int i4 = blockIdx.x * 256 + threadIdx.x;            // float4 index
  if (i4 >= NN * D / 4) return;
  int d = (i4 & 31) * 4;
  float4 v = reinterpret_cast<const float4*>(x0)[i4];
  float4 e = *reinterpret_cast<const float4*>(eps + d);
  v.x *= (1.f + e.x); v.y *= (1.f + e.y); v.z *= (1.f + e.z); v.w *= (1.f + e.w);
  reinterpret_cast<float4*>(result)[i4] = v;
}

// ---------------------------------------------------------------------------
// One wave (64 lanes) per edge; lane handles 2 consecutive features.
// msg = relu(x[src] + edge_attr?) * (1+eps[hop+1]); atomicAdd into result[dst].
__global__ __launch_bounds__(256) void k_scatter(
    const float* __restrict__ x0, const float* __restrict__ x1,
    const float* __restrict__ x2, const float* __restrict__ x3,
    const int* __restrict__ e0, const int* __restrict__ e1,
    const int* __restrict__ e2, const int* __restrict__ e3,
    const float* __restrict__ edge_attr, const float* __restrict__ eps,
    float* __restrict__ result) {
  const int hop = blockIdx.y;
  const float* x; const int* e;
  switch (hop) {
    case 0:  x = x0; e = e0; break;
    case 1:  x = x1; e = e1; break;
    case 2:  x = x2; e = e2; break;
    default: x = x3; e = e3; break;
  }
  const int eid  = blockIdx.x * 4 + (threadIdx.x >> 6);   // grid.x = NE/4 exact
  const int lane = threadIdx.x & 63;
  const int d    = lane * 2;
  const int src  = e[eid];
  const int dst  = e[NE + eid];

  float2 v = *reinterpret_cast<const float2*>(x + (size_t)src * D + d);
  if (hop == 0) {
    float2 ea = *reinterpret_cast<const float2*>(edge_attr + (size_t)eid * D + d);
    v.x += ea.x; v.y += ea.y;
  }
  v.x = fmaxf(v.x, 0.f); v.y = fmaxf(v.y, 0.f);
  float2 s = *reinterpret_cast<const float2*>(eps + (hop + 1) * D + d);
  v.x *= (1.f + s.x); v.y *= (1.f + s.y);

  float* r = result + (size_t)dst * D + d;
  unsafeAtomicAdd(r,     v.x);
  unsafeAtomicAdd(r + 1, v.y);
}

// ---------------------------------------------------------------------------
// GEMM1: C[N,256] = A[N,128] @ B[128,256]   (bias b1 omitted: cancels in BN1)
// block: 512 thr, tile 128x256, BK=32, thread tile 8x(4+4)
__global__ __launch_bounds__(512) void k_gemm1(const float* __restrict__ A,
                                               const float* __restrict__ B,
                                               float* __restrict__ C) {
  __shared__ float As[32][132];   // [k][row], padded: 132%4==0 (16B-aligned rows)
  __shared__ float Bs[32][256];   // [k][col]
  const int tid = threadIdx.x;
  const int tx = tid & 31, ty = tid >> 5;
  const int row0 = blockIdx.x * 128;

  float acc[8][8];
#pragma unroll
  for (int i = 0; i < 8; i++)
#pragma unroll
    for (int j = 0; j < 8; j++) acc[i][j] = 0.f;

  for (int k0 = 0; k0 < 128; k0 += 32) {
#pragma unroll
    for (int l = 0; l < 2; l++) {               // A tile 128x32 -> transposed LDS
      int f4 = tid + l * 512;
      int row = f4 >> 3, kq = f4 & 7;
      float4 v = make_float4(0.f, 0.f, 0.f, 0.f);
      if (row0 + row < NN)
        v = *reinterpret_cast<const float4*>(A + (size_t)(row0 + row) * 128 + k0 + kq * 4);
      As[kq * 4 + 0][row] = v.x; As[kq * 4 + 1][row] = v.y;
      As[kq * 4 + 2][row] = v.z; As[kq * 4 + 3][row] = v.w;
    }
#pragma unroll
    for (int l = 0; l < 4; l++) {               // B tile 32x256
      int f4 = tid + l * 512;
      int kk = f4 >> 6, cq = f4 & 63;
      *reinterpret_cast<float4*>(&Bs[kk][cq * 4]) =
          *reinterpret_cast<const float4*>(B + (size_t)(k0 + kk) * 256 + cq * 4);
    }
    __syncthreads();
#pragma unroll
    for (int k = 0; k < 32; k++) {
      float a[8], b[8];
      *reinterpret_cast<float4*>(a)     = *reinterpret_cast<const float4*>(&As[k][ty * 8]);
      *reinterpret_cast<float4*>(a + 4) = *reinterpret_cast<const float4*>(&As[k][ty * 8 + 4]);
      *reinterpret_cast<float4*>(b)     = *reinterpret_cast<const float4*>(&Bs[k][tx * 4]);
      *reinterpret_cast<float4*>(b + 4) = *reinterpret_cast<const float4*>(&Bs[k][128 + tx * 4]);
#pragma unroll
      for (int i = 0; i < 8; i++)
#pragma unroll
        for (int j = 0; j < 8; j++) acc[i][j] = fmaf(a[i], b[j], acc[i][j]);
    }
    __syncthreads();
  }
#pragma unroll
  for (int i = 0; i < 8; i++) {
    int row = row0 + ty * 8 + i;
    if (row < NN) {
      *reinterpret_cast<float4*>(C + (size_t)row * 256 + tx * 4) =
          make_float4(acc[i][0], acc[i][1], acc[i][2], acc[i][3]);
      *reinterpret_cast<float4*>(C + (size_t)row * 256 + 128 + tx * 4) =
          make_float4(acc[i][4], acc[i][5], acc[i][6], acc[i][7]);
    }
  }
}

// ---------------------------------------------------------------------------
// GEMM2: C[N,128] = relu(scale1*t1+shift1)[N,256] @ W2[256,128]  (b2 omitted)
__global__ __launch_bounds__(512) void k_gemm2(const float* __restrict__ A,
                                               const float* __restrict__ B,
                                               const float* __restrict__ sc,
                                               const float* __restrict__ sh,
                                               float* __restrict__ C) {
  __shared__ float As[32][132];
  __shared__ float Bs[32][128];
  const int tid = threadIdx.x;
  const int tx = tid & 31, ty = tid >> 5;
  const int row0 = blockIdx.x * 128;

  float acc[8][4];
#pragma unroll
  for (int i = 0; i < 8; i++)
#pragma unroll
    for (int j = 0; j < 4; j++) acc[i][j] = 0.f;

  for (int k0 = 0; k0 < 256; k0 += 32) {
#pragma unroll
    for (int l = 0; l < 2; l++) {               // A tile 128x32 with bn1+relu
      int f4 = tid + l * 512;
      int row = f4 >> 3, kq = f4 & 7;
      float4 v = make_float4(0.f, 0.f, 0.f, 0.f);
      if (row0 + row < NN)
        v = *reinterpret_cast<const float4*>(A + (size_t)(row0 + row) * 256 + k0 + kq * 4);
      float4 s  = *reinterpret_cast<const float4*>(sc + k0 + kq * 4);
      float4 hh = *reinterpret_cast<const float4*>(sh + k0 + kq * 4);
      v.x = fmaxf(fmaf(s.x, v.x, hh.x), 0.f);
      v.y = fmaxf(fmaf(s.y, v.y, hh.y), 0.f);
      v.z = fmaxf(fmaf(s.z, v.z, hh.z), 0.f);
      v.w = fmaxf(fmaf(s.w, v.w, hh.w), 0.f);
      As[kq * 4 + 0][row] = v.x; As[kq * 4 + 1][row] = v.y;
      As[kq * 4 + 2][row] = v.z; As[kq * 4 + 3][row] = v.w;
    }
#pragma unroll
    for (int l = 0; l < 2; l++) {               // B tile 32x128
      int f4 = tid + l * 512;
      int kk = f4 >> 5, cq = f4 & 31;
      *reinterpret_cast<float4*>(&Bs[kk][cq * 4]) =
          *reinterpret_cast<const float4*>(B + (size_t)(k0 + kk) * 128 + cq * 4);
    }
    __syncthreads();
#pragma unroll
    for (int k = 0; k < 32; k++) {
      float a[8], b[4];
      *reinterpret_cast<float4*>(a)     = *reinterpret_cast<const float4*>(&As[k][ty * 8]);
      *reinterpret_cast<float4*>(a + 4) = *reinterpret_cast<const float4*>(&As[k][ty * 8 + 4]);
      *reinterpret_cast<float4*>(b)     = *reinterpret_cast<const float4*>(&Bs[k][tx * 4]);
#pragma unroll
      for (int i = 0; i < 8; i++)
#pragma unroll
        for (int j = 0; j < 4; j++) acc[i][j] = fmaf(a[i], b[j], acc[i][j]);
    }
    __syncthreads();
  }
#pragma unroll
  for (int i = 0; i < 8; i++) {
    int row = row0 + ty * 8 + i;
    if (row < NN)
      *reinterpret_cast<float4*>(C + (size_t)row * 128 + tx * 4) =
          make_float4(acc[i][0], acc[i][1], acc[i][2], acc[i][3]);
  }
}

// ---------------------------------------------------------------------------
// Per-column sum / sumsq over N rows (optionally through relu(sc*x+sh)).
// stride (grid*256) is a multiple of C -> each thread owns one column.
template <int C, bool ACT>
__global__ __launch_bounds__(256) void k_colstats(const float* __restrict__ X,
                                                  const float* __restrict__ sc,
                                                  const float* __restrict__ sh,
                                                  float* __restrict__ sums,
                                                  float* __restrict__ sumsq) {
  const long total = (long)NN * C;
  const long stride = (long)gridDim.x * 256;
  const long start = (long)blockIdx.x * 256 + threadIdx.x;
  const int c = (int)(start & (C - 1));
  float scale = 0.f, shiftv = 0.f;
  if constexpr (ACT) { scale = sc[c]; shiftv = sh[c]; }
  float s = 0.f, q = 0.f;
  for (long idx = start; idx < total; idx += stride) {
    float v = X[idx];
    if constexpr (ACT) v = fmaxf(fmaf(scale, v, shiftv), 0.f);
    s += v;
    q = fmaf(v, v, q);
  }
  unsafeAtomicAdd(&sums[c], s);
  unsafeAtomicAdd(&sumsq[c], q);
}

template <int C>
__global__ void k_bnfinal(const float* __restrict__ sums, const float* __restrict__ sumsq,
                          const float* __restrict__ g, const float* __restrict__ b,
                          float* __restrict__ scale, float* __restrict__ shift) {
  int c = threadIdx.x;
  if (c >= C) return;
  float mean = sums[c] * (1.f / NN);
  float var  = sumsq[c] * (1.f / NN) - mean * mean;
  float rs   = rsqrtf(var + BN_EPS);
  float s    = g[c] * rs;
  scale[c] = s;
  shift[c] = b[c] - mean * s;
}

// out = relu(s3 * relu(s2*t2+h2) + h3), in place on d_out
__global__ __launch_bounds__(256) void k_final(float* __restrict__ t2,
                                               const float* __restrict__ s2, const float* __restrict__ h2,
                                               const float* __restrict__ s3, const float* __restrict__ h3) {
  int i4 = blockIdx.x * 256 + threadIdx.x;
  if (i4 >= NN * D / 4) return;
  int d = (i4 & 31) * 4;
  float4 v  = reinterpret_cast<float4*>(t2)[i4];
  float4 a2 = *reinterpret_cast<const float4*>(s2 + d);
  float4 b2 = *reinterpret_cast<const float4*>(h2 + d);
  float4 a3 = *reinterpret_cast<const float4*>(s3 + d);
  float4 b3 = *reinterpret_cast<const float4*>(h3 + d);
  v.x = fmaxf(fmaf(a3.x, fmaxf(fmaf(a2.x, v.x, b2.x), 0.f), b3.x), 0.f);
  v.y = fmaxf(fmaf(a3.y, fmaxf(fmaf(a2.y, v.y, b2.y), 0.f), b3.y), 0.f);
  v.z = fmaxf(fmaf(a3.z, fmaxf(fmaf(a2.z, v.z, b2.z), 0.f), b3.z), 0.f);
  v.w = fmaxf(fmaf(a3.w, fmaxf(fmaf(a2.w, v.w, b2.w), 0.f), b3.w), 0.f);
  reinterpret_cast<float4*>(t2)[i4] = v;
}

// ---------------------------------------------------------------------------
extern "C" void kernel_launch(void* const* d_in, const int* in_sizes, int n_in,
                              void* d_out, int out_size, void* d_ws, size_t ws_size,
                              hipStream_t stream) {
  const float* x0 = (const float*)d_in[0];
  const float* x1 = (const float*)d_in[1];
  const float* x2 = (const float*)d_in[2];
  const float* x3 = (const float*)d_in[3];
  const float* edge_attr = (const float*)d_in[4];
  const int* e0 = (const int*)d_in[5];
  const int* e1 = (const int*)d_in[6];
  const int* e2 = (const int*)d_in[7];
  const int* e3 = (const int*)d_in[8];
  const float* W1 = (const float*)d_in[9];
  // d_in[10] = b1 (cancels in BN1)
  const float* bn1_g = (const float*)d_in[11];
  const float* bn1_b = (const float*)d_in[12];
  const float* W2 = (const float*)d_in[13];
  // d_in[14] = b2 (cancels in BN2)
  const float* bn2_g = (const float*)d_in[15];
  const float* bn2_b = (const float*)d_in[16];
  const float* bn3_g = (const float*)d_in[17];
  const float* bn3_b = (const float*)d_in[18];
  const float* eps = (const float*)d_in[19];

  float* ws = (float*)d_ws;
  float* result = ws;                               // N*128
  float* t1 = ws + (size_t)NN * D;                  // N*256
  float* stats = t1 + (size_t)NN * 256;
  float* sums1 = stats;            // 256
  float* sumsq1 = sums1 + 256;     // 256
  float* sums2 = sumsq1 + 256;     // 128
  float* sumsq2 = sums2 + 128;     // 128
  float* sums3 = sumsq2 + 128;     // 128
  float* sumsq3 = sums3 + 128;     // 128
  float* scale1 = sumsq3 + 128;    // 256
  float* shift1 = scale1 + 256;    // 256
  float* scale2 = shift1 + 256;    // 128
  float* shift2 = scale2 + 128;    // 128
  float* scale3 = shift2 + 128;    // 128
  float* shift3 = scale3 + 128;    // 128
  float* t2 = (float*)d_out;                        // reuse output as t2

  hipMemsetAsync(stats, 0, 1024 * sizeof(float), stream);

  k_init<<<NN * D / 4 / 256, 256, 0, stream>>>(x0, eps, result);
  k_scatter<<<dim3(NE / 4, 4), 256, 0, stream>>>(x0, x1, x2, x3, e0, e1, e2, e3,
                                                 edge_attr, eps, result);
  k_gemm1<<<(NN + 127) / 128, 512, 0, stream>>>(result, W1, t1);
  k_colstats<256, false><<<512, 256, 0, stream>>>(t1, nullptr, nullptr, sums1, sumsq1);
  k_bnfinal<256><<<1, 256, 0, stream>>>(sums1, sumsq1, bn1_g, bn1_b, scale1, shift1);
  k_gemm2<<<(NN + 127) / 128, 512, 0, stream>>>(t1, W2, scale1, shift1, t2);
  k_colstats<128, false><<<512, 256, 0, stream>>>(t2, nullptr, nullptr, sums2, sumsq2);
  k_bnfinal<128><<<1, 128, 0, stream>>>(sums2, sumsq2, bn2_g, bn2_b, scale2, shift2);
  k_colstats<128, true><<<512, 256, 0, stream>>>(t2, scale2, shift2, sums3, sumsq3);
  k_bnfinal<128><<<1, 128, 0, stream>>>(sums3, sumsq3, bn3_g, bn3_b, scale3, shift3);
  k_final<<<NN * D / 4 / 256, 256, 0, stream>>>(t2, scale2, shift2, scale3, shift3);
}

// Round 2
// 1203.790 us; speedup vs baseline: 2.5051x; 2.5051x over previous
//
#include <hip/hip_runtime.h>
#include <cstdint>
#include <cstddef>

#define NN 100000
#define D 128
#define NE 800000
#define BN_EPS 1e-5f

#define M4 (4 * NN)     // total buckets (hop-major)
#define CH 1000         // scan chunk
#define NB 400          // M4 / CH

// ---------------------------------------------------------------------------
// CSR build: in-degree count per (hop, dst)
__global__ __launch_bounds__(256) void k_count(
    const int* __restrict__ e0, const int* __restrict__ e1,
    const int* __restrict__ e2, const int* __restrict__ e3,
    int* __restrict__ counts) {
  const int h = blockIdx.y;
  const int* e = h == 0 ? e0 : h == 1 ? e1 : h == 2 ? e2 : e3;
  const int eid = blockIdx.x * 256 + threadIdx.x;   // grid.x = NE/256 exact
  const int dst = e[NE + eid];
  atomicAdd(&counts[h * NN + dst], 1);
}

// chunk sums
__global__ __launch_bounds__(256) void k_scanA(const int* __restrict__ counts,
                                               int* __restrict__ bsum) {
  __shared__ int red[256];
  const int b = blockIdx.x, t = threadIdx.x;
  int s = 0;
  for (int i = t; i < CH; i += 256) s += counts[b * CH + i];
  red[t] = s; __syncthreads();
  for (int off = 128; off > 0; off >>= 1) {
    if (t < off) red[t] += red[t + off];
    __syncthreads();
  }
  if (t == 0) bsum[b] = red[0];
}

// exclusive scan of chunk sums (NB=400 <= 512)
__global__ __launch_bounds__(512) void k_scanB(const int* __restrict__ bsum,
                                               int* __restrict__ bpre) {
  __shared__ int s[512];
  const int t = threadIdx.x;
  const int v = (t < NB) ? bsum[t] : 0;
  s[t] = v; __syncthreads();
  for (int off = 1; off < 512; off <<= 1) {
    int x = s[t];
    if (t >= off) x += s[t - off];
    __syncthreads(); s[t] = x; __syncthreads();
  }
  if (t < NB) bpre[t] = s[t] - v;
}

// per-chunk exclusive scan -> offsets (and cursor copy for fill)
__global__ __launch_bounds__(256) void k_scanC(const int* __restrict__ counts,
                                               const int* __restrict__ bpre,
                                               int* __restrict__ offsets,
                                               int* __restrict__ cursor) {
  __shared__ int cnt[CH];
  __shared__ int part[256];
  const int b = blockIdx.x, t = threadIdx.x;
  for (int i = t; i < CH; i += 256) cnt[i] = counts[b * CH + i];
  __syncthreads();
  int own = 0;
#pragma unroll
  for (int j = 0; j < 4; j++) {
    int idx = t * 4 + j;
    if (idx < CH) own += cnt[idx];
  }
  part[t] = own; __syncthreads();
  for (int off = 1; off < 256; off <<= 1) {        // inclusive scan
    int x = part[t];
    if (t >= off) x += part[t - off];
    __syncthreads(); part[t] = x; __syncthreads();
  }
  int run = bpre[b] + part[t] - own;               // exclusive within chunk
#pragma unroll
  for (int j = 0; j < 4; j++) {
    int idx = t * 4 + j;
    if (idx < CH) {
      offsets[b * CH + idx] = run;
      cursor[b * CH + idx] = run;
      run += cnt[idx];
    }
  }
  if (b == 0 && t == 0) offsets[M4] = 4 * NE;
}

// fill buckets: srcs (all hops), eids (hop 0 region only, positions < NE)
__global__ __launch_bounds__(256) void k_fill(
    const int* __restrict__ e0, const int* __restrict__ e1,
    const int* __restrict__ e2, const int* __restrict__ e3,
    int* __restrict__ cursor, int* __restrict__ srcs, int* __restrict__ eids) {
  const int h = blockIdx.y;
  const int* e = h == 0 ? e0 : h == 1 ? e1 : h == 2 ? e2 : e3;
  const int eid = blockIdx.x * 256 + threadIdx.x;
  const int src = e[eid];
  const int dst = e[NE + eid];
  const int pos = atomicAdd(&cursor[h * NN + dst], 1);
  srcs[pos] = src;
  if (h == 0) eids[pos] = eid;
}

// ---------------------------------------------------------------------------
// One wave per dst node. acc = (1+eps0)*x0[dst] + sum_h (1+eps_{h+1})*sum_e relu(...)
// All accumulation in registers; single write, no float atomics.
__global__ __launch_bounds__(256) void k_gather(
    const float* __restrict__ x0, const float* __restrict__ x1,
    const float* __restrict__ x2, const float* __restrict__ x3,
    const float* __restrict__ edge_attr, const float* __restrict__ eps,
    const int* __restrict__ offsets, const int* __restrict__ srcs,
    const int* __restrict__ eids, float* __restrict__ result) {
  const int dst  = blockIdx.x * 4 + (threadIdx.x >> 6);   // grid.x = NN/4 exact
  const int lane = threadIdx.x & 63;
  const int d    = lane * 2;

  float2 ev = *reinterpret_cast<const float2*>(eps + d);
  float2 v0 = *reinterpret_cast<const float2*>(x0 + (size_t)dst * D + d);
  float2 acc;
  acc.x = (1.f + ev.x) * v0.x;
  acc.y = (1.f + ev.y) * v0.y;

#pragma unroll
  for (int h = 0; h < 4; ++h) {
    const float* __restrict__ xh = h == 0 ? x0 : h == 1 ? x1 : h == 2 ? x2 : x3;
    float2 sc = *reinterpret_cast<const float2*>(eps + (h + 1) * D + d);
    sc.x += 1.f; sc.y += 1.f;
    const int beg = offsets[h * NN + dst];
    const int end = offsets[h * NN + dst + 1];
    for (int j = beg; j < end; ++j) {
      const int src = srcs[j];
      float2 v = *reinterpret_cast<const float2*>(xh + (size_t)src * D + d);
      if (h == 0) {
        const int eid = eids[j];
        float2 a = *reinterpret_cast<const float2*>(edge_attr + (size_t)eid * D + d);
        v.x += a.x; v.y += a.y;
      }
      acc.x += sc.x * fmaxf(v.x, 0.f);
      acc.y += sc.y * fmaxf(v.y, 0.f);
    }
  }
  *reinterpret_cast<float2*>(result + (size_t)dst * D + d) = acc;
}

// ---------------------------------------------------------------------------
// GEMM1: C[N,256] = A[N,128] @ B[128,256]   (bias b1 omitted: cancels in BN1)
__global__ __launch_bounds__(512) void k_gemm1(const float* __restrict__ A,
                                               const float* __restrict__ B,
                                               float* __restrict__ C) {
  __shared__ float As[32][132];
  __shared__ float Bs[32][256];
  const int tid = threadIdx.x;
  const int tx = tid & 31, ty = tid >> 5;
  const int row0 = blockIdx.x * 128;

  float acc[8][8];
#pragma unroll
  for (int i = 0; i < 8; i++)
#pragma unroll
    for (int j = 0; j < 8; j++) acc[i][j] = 0.f;

  for (int k0 = 0; k0 < 128; k0 += 32) {
#pragma unroll
    for (int l = 0; l < 2; l++) {
      int f4 = tid + l * 512;
      int row = f4 >> 3, kq = f4 & 7;
      float4 v = make_float4(0.f, 0.f, 0.f, 0.f);
      if (row0 + row < NN)
        v = *reinterpret_cast<const float4*>(A + (size_t)(row0 + row) * 128 + k0 + kq * 4);
      As[kq * 4 + 0][row] = v.x; As[kq * 4 + 1][row] = v.y;
      As[kq * 4 + 2][row] = v.z; As[kq * 4 + 3][row] = v.w;
    }
#pragma unroll
    for (int l = 0; l < 4; l++) {
      int f4 = tid + l * 512;
      int kk = f4 >> 6, cq = f4 & 63;
      *reinterpret_cast<float4*>(&Bs[kk][cq * 4]) =
          *reinterpret_cast<const float4*>(B + (size_t)(k0 + kk) * 256 + cq * 4);
    }
    __syncthreads();
#pragma unroll
    for (int k = 0; k < 32; k++) {
      float a[8], b[8];
      *reinterpret_cast<float4*>(a)     = *reinterpret_cast<const float4*>(&As[k][ty * 8]);
      *reinterpret_cast<float4*>(a + 4) = *reinterpret_cast<const float4*>(&As[k][ty * 8 + 4]);
      *reinterpret_cast<float4*>(b)     = *reinterpret_cast<const float4*>(&Bs[k][tx * 4]);
      *reinterpret_cast<float4*>(b + 4) = *reinterpret_cast<const float4*>(&Bs[k][128 + tx * 4]);
#pragma unroll
      for (int i = 0; i < 8; i++)
#pragma unroll
        for (int j = 0; j < 8; j++) acc[i][j] = fmaf(a[i], b[j], acc[i][j]);
    }
    __syncthreads();
  }
#pragma unroll
  for (int i = 0; i < 8; i++) {
    int row = row0 + ty * 8 + i;
    if (row < NN) {
      *reinterpret_cast<float4*>(C + (size_t)row * 256 + tx * 4) =
          make_float4(acc[i][0], acc[i][1], acc[i][2], acc[i][3]);
      *reinterpret_cast<float4*>(C + (size_t)row * 256 + 128 + tx * 4) =
          make_float4(acc[i][4], acc[i][5], acc[i][6], acc[i][7]);
    }
  }
}

// ---------------------------------------------------------------------------
// GEMM2: C[N,128] = relu(scale1*t1+shift1)[N,256] @ W2[256,128]  (b2 omitted)
__global__ __launch_bounds__(512) void k_gemm2(const float* __restrict__ A,
                                               const float* __restrict__ B,
                                               const float* __restrict__ sc,
                                               const float* __restrict__ sh,
                                               float* __restrict__ C) {
  __shared__ float As[32][132];
  __shared__ float Bs[32][128];
  const int tid = threadIdx.x;
  const int tx = tid & 31, ty = tid >> 5;
  const int row0 = blockIdx.x * 128;

  float acc[8][4];
#pragma unroll
  for (int i = 0; i < 8; i++)
#pragma unroll
    for (int j = 0; j < 4; j++) acc[i][j] = 0.f;

  for (int k0 = 0; k0 < 256; k0 += 32) {
#pragma unroll
    for (int l = 0; l < 2; l++) {
      int f4 = tid + l * 512;
      int row = f4 >> 3, kq = f4 & 7;
      float4 v = make_float4(0.f, 0.f, 0.f, 0.f);
      if (row0 + row < NN)
        v = *reinterpret_cast<const float4*>(A + (size_t)(row0 + row) * 256 + k0 + kq * 4);
      float4 s  = *reinterpret_cast<const float4*>(sc + k0 + kq * 4);
      float4 hh = *reinterpret_cast<const float4*>(sh + k0 + kq * 4);
      v.x = fmaxf(fmaf(s.x, v.x, hh.x), 0.f);
      v.y = fmaxf(fmaf(s.y, v.y, hh.y), 0.f);
      v.z = fmaxf(fmaf(s.z, v.z, hh.z), 0.f);
      v.w = fmaxf(fmaf(s.w, v.w, hh.w), 0.f);
      As[kq * 4 + 0][row] = v.x; As[kq * 4 + 1][row] = v.y;
      As[kq * 4 + 2][row] = v.z; As[kq * 4 + 3][row] = v.w;
    }
#pragma unroll
    for (int l = 0; l < 2; l++) {
      int f4 = tid + l * 512;
      int kk = f4 >> 5, cq = f4 & 31;
      *reinterpret_cast<float4*>(&Bs[kk][cq * 4]) =
          *reinterpret_cast<const float4*>(B + (size_t)(k0 + kk) * 128 + cq * 4);
    }
    __syncthreads();
#pragma unroll
    for (int k = 0; k < 32; k++) {
      float a[8], b[4];
      *reinterpret_cast<float4*>(a)     = *reinterpret_cast<const float4*>(&As[k][ty * 8]);
      *reinterpret_cast<float4*>(a + 4) = *reinterpret_cast<const float4*>(&As[k][ty * 8 + 4]);
      *reinterpret_cast<float4*>(b)     = *reinterpret_cast<const float4*>(&Bs[k][tx * 4]);
#pragma unroll
      for (int i = 0; i < 8; i++)
#pragma unroll
        for (int j = 0; j < 4; j++) acc[i][j] = fmaf(a[i], b[j], acc[i][j]);
    }
    __syncthreads();
  }
#pragma unroll
  for (int i = 0; i < 8; i++) {
    int row = row0 + ty * 8 + i;
    if (row < NN)
      *reinterpret_cast<float4*>(C + (size_t)row * 128 + tx * 4) =
          make_float4(acc[i][0], acc[i][1], acc[i][2], acc[i][3]);
  }
}

// ---------------------------------------------------------------------------
template <int C, bool ACT>
__global__ __launch_bounds__(256) void k_colstats(const float* __restrict__ X,
                                                  const float* __restrict__ sc,
                                                  const float* __restrict__ sh,
                                                  float* __restrict__ sums,
                                                  float* __restrict__ sumsq) {
  const long total = (long)NN * C;
  const long stride = (long)gridDim.x * 256;
  const long start = (long)blockIdx.x * 256 + threadIdx.x;
  const int c = (int)(start & (C - 1));
  float scale = 0.f, shiftv = 0.f;
  if constexpr (ACT) { scale = sc[c]; shiftv = sh[c]; }
  float s = 0.f, q = 0.f;
  for (long idx = start; idx < total; idx += stride) {
    float v = X[idx];
    if constexpr (ACT) v = fmaxf(fmaf(scale, v, shiftv), 0.f);
    s += v;
    q = fmaf(v, v, q);
  }
  unsafeAtomicAdd(&sums[c], s);
  unsafeAtomicAdd(&sumsq[c], q);
}

template <int C>
__global__ void k_bnfinal(const float* __restrict__ sums, const float* __restrict__ sumsq,
                          const float* __restrict__ g, const float* __restrict__ b,
                          float* __restrict__ scale, float* __restrict__ shift) {
  int c = threadIdx.x;
  if (c >= C) return;
  float mean = sums[c] * (1.f / NN);
  float var  = sumsq[c] * (1.f / NN) - mean * mean;
  float rs   = rsqrtf(var + BN_EPS);
  float s    = g[c] * rs;
  scale[c] = s;
  shift[c] = b[c] - mean * s;
}

// out = relu(s3 * relu(s2*t2+h2) + h3), in place on d_out
__global__ __launch_bounds__(256) void k_final(float* __restrict__ t2,
                                               const float* __restrict__ s2, const float* __restrict__ h2,
                                               const float* __restrict__ s3, const float* __restrict__ h3) {
  int i4 = blockIdx.x * 256 + threadIdx.x;
  if (i4 >= NN * D / 4) return;
  int d = (i4 & 31) * 4;
  float4 v  = reinterpret_cast<float4*>(t2)[i4];
  float4 a2 = *reinterpret_cast<const float4*>(s2 + d);
  float4 b2 = *reinterpret_cast<const float4*>(h2 + d);
  float4 a3 = *reinterpret_cast<const float4*>(s3 + d);
  float4 b3 = *reinterpret_cast<const float4*>(h3 + d);
  v.x = fmaxf(fmaf(a3.x, fmaxf(fmaf(a2.x, v.x, b2.x), 0.f), b3.x), 0.f);
  v.y = fmaxf(fmaf(a3.y, fmaxf(fmaf(a2.y, v.y, b2.y), 0.f), b3.y), 0.f);
  v.z = fmaxf(fmaf(a3.z, fmaxf(fmaf(a2.z, v.z, b2.z), 0.f), b3.z), 0.f);
  v.w = fmaxf(fmaf(a3.w, fmaxf(fmaf(a2.w, v.w, b2.w), 0.f), b3.w), 0.f);
  reinterpret_cast<float4*>(t2)[i4] = v;
}

// ---------------------------------------------------------------------------
extern "C" void kernel_launch(void* const* d_in, const int* in_sizes, int n_in,
                              void* d_out, int out_size, void* d_ws, size_t ws_size,
                              hipStream_t stream) {
  const float* x0 = (const float*)d_in[0];
  const float* x1 = (const float*)d_in[1];
  const float* x2 = (const float*)d_in[2];
  const float* x3 = (const float*)d_in[3];
  const float* edge_attr = (const float*)d_in[4];
  const int* e0 = (const int*)d_in[5];
  const int* e1 = (const int*)d_in[6];
  const int* e2 = (const int*)d_in[7];
  const int* e3 = (const int*)d_in[8];
  const float* W1 = (const float*)d_in[9];
  // d_in[10] = b1 (cancels in BN1)
  const float* bn1_g = (const float*)d_in[11];
  const float* bn1_b = (const float*)d_in[12];
  const float* W2 = (const float*)d_in[13];
  // d_in[14] = b2 (cancels in BN2)
  const float* bn2_g = (const float*)d_in[15];
  const float* bn2_b = (const float*)d_in[16];
  const float* bn3_g = (const float*)d_in[17];
  const float* bn3_b = (const float*)d_in[18];
  const float* eps = (const float*)d_in[19];

  float* ws = (float*)d_ws;
  float* result = ws;                               // N*128 floats
  float* t1 = ws + (size_t)NN * D;                  // N*256 floats

  // CSR arrays alias the t1 region (dead until k_gemm1 writes t1)
  int* counts  = (int*)t1;                          // 400000
  int* offsets = counts + M4;                       // 400001
  int* cursor  = offsets + M4 + 1;                  // 400000
  int* bsum    = cursor + M4;                       // 400
  int* bpre    = bsum + NB;                         // 400
  int* srcs    = bpre + NB;                         // 3200000
  int* eids    = srcs + 4 * NE;                     // 800000 (hop-0 region only)

  float* stats = t1 + (size_t)NN * 256;
  float* sums1 = stats;            // 256
  float* sumsq1 = sums1 + 256;     // 256
  float* sums2 = sumsq1 + 256;     // 128
  float* sumsq2 = sums2 + 128;     // 128
  float* sums3 = sumsq2 + 128;     // 128
  float* sumsq3 = sums3 + 128;     // 128
  float* scale1 = sumsq3 + 128;    // 256
  float* shift1 = scale1 + 256;    // 256
  float* scale2 = shift1 + 256;    // 128
  float* shift2 = scale2 + 128;    // 128
  float* scale3 = shift2 + 128;    // 128
  float* shift3 = scale3 + 128;    // 128
  float* t2 = (float*)d_out;                        // reuse output as t2

  hipMemsetAsync(counts, 0, M4 * sizeof(int), stream);
  hipMemsetAsync(stats, 0, 1024 * sizeof(float), stream);

  // CSR build
  k_count<<<dim3(NE / 256, 4), 256, 0, stream>>>(e0, e1, e2, e3, counts);
  k_scanA<<<NB, 256, 0, stream>>>(counts, bsum);
  k_scanB<<<1, 512, 0, stream>>>(bsum, bpre);
  k_scanC<<<NB, 256, 0, stream>>>(counts, bpre, offsets, cursor);
  k_fill<<<dim3(NE / 256, 4), 256, 0, stream>>>(e0, e1, e2, e3, cursor, srcs, eids);

  // register-resident aggregation, one wave per node
  k_gather<<<NN / 4, 256, 0, stream>>>(x0, x1, x2, x3, edge_attr, eps,
                                       offsets, srcs, eids, result);

  // MLP + BNs
  k_gemm1<<<(NN + 127) / 128, 512, 0, stream>>>(result, W1, t1);
  k_colstats<256, false><<<512, 256, 0, stream>>>(t1, nullptr, nullptr, sums1, sumsq1);
  k_bnfinal<256><<<1, 256, 0, stream>>>(sums1, sumsq1, bn1_g, bn1_b, scale1, shift1);
  k_gemm2<<<(NN + 127) / 128, 512, 0, stream>>>(t1, W2, scale1, shift1, t2);
  k_colstats<128, false><<<512, 256, 0, stream>>>(t2, nullptr, nullptr, sums2, sumsq2);
  k_bnfinal<128><<<1, 128, 0, stream>>>(sums2, sumsq2, bn2_g, bn2_b, scale2, shift2);
  k_colstats<128, true><<<512, 256, 0, stream>>>(t2, scale2, shift2, sums3, sumsq3);
  k_bnfinal<128><<<1, 128, 0, stream>>>(sums3, sumsq3, bn3_g, bn3_b, scale3, shift3);
  k_final<<<NN * D / 4 / 256, 256, 0, stream>>>(t2, scale2, shift2, scale3, shift3);
}

// Round 3
// 905.842 us; speedup vs baseline: 3.3291x; 1.3289x over previous
//
#include <hip/hip_runtime.h>
#include <cstdint>
#include <cstddef>

#define NN 100000
#define D 128
#define NE 800000
#define BN_EPS 1e-5f

#define M4 (4 * NN)     // total buckets (dst-major: dst*4 + hop)
#define CH 1000         // scan chunk
#define NB 400          // M4 / CH

// ---------------------------------------------------------------------------
// CSR build: in-degree count per (dst, hop)
__global__ __launch_bounds__(256) void k_count(
    const int* __restrict__ e0, const int* __restrict__ e1,
    const int* __restrict__ e2, const int* __restrict__ e3,
    int* __restrict__ counts) {
  const int h = blockIdx.y;
  const int* e = h == 0 ? e0 : h == 1 ? e1 : h == 2 ? e2 : e3;
  const int eid = blockIdx.x * 256 + threadIdx.x;   // grid.x = NE/256 exact
  const int dst = e[NE + eid];
  atomicAdd(&counts[dst * 4 + h], 1);
}

// chunk sums
__global__ __launch_bounds__(256) void k_scanA(const int* __restrict__ counts,
                                               int* __restrict__ bsum) {
  __shared__ int red[256];
  const int b = blockIdx.x, t = threadIdx.x;
  int s = 0;
  for (int i = t; i < CH; i += 256) s += counts[b * CH + i];
  red[t] = s; __syncthreads();
  for (int off = 128; off > 0; off >>= 1) {
    if (t < off) red[t] += red[t + off];
    __syncthreads();
  }
  if (t == 0) bsum[b] = red[0];
}

// exclusive scan of chunk sums (NB=400 <= 512)
__global__ __launch_bounds__(512) void k_scanB(const int* __restrict__ bsum,
                                               int* __restrict__ bpre) {
  __shared__ int s[512];
  const int t = threadIdx.x;
  const int v = (t < NB) ? bsum[t] : 0;
  s[t] = v; __syncthreads();
  for (int off = 1; off < 512; off <<= 1) {
    int x = s[t];
    if (t >= off) x += s[t - off];
    __syncthreads(); s[t] = x; __syncthreads();
  }
  if (t < NB) bpre[t] = s[t] - v;
}

// per-chunk exclusive scan -> offsets (and cursor copy for fill)
__global__ __launch_bounds__(256) void k_scanC(const int* __restrict__ counts,
                                               const int* __restrict__ bpre,
                                               int* __restrict__ offsets,
                                               int* __restrict__ cursor) {
  __shared__ int cnt[CH];
  __shared__ int part[256];
  const int b = blockIdx.x, t = threadIdx.x;
  for (int i = t; i < CH; i += 256) cnt[i] = counts[b * CH + i];
  __syncthreads();
  int own = 0;
#pragma unroll
  for (int j = 0; j < 4; j++) {
    int idx = t * 4 + j;
    if (idx < CH) own += cnt[idx];
  }
  part[t] = own; __syncthreads();
  for (int off = 1; off < 256; off <<= 1) {        // inclusive scan
    int x = part[t];
    if (t >= off) x += part[t - off];
    __syncthreads(); part[t] = x; __syncthreads();
  }
  int run = bpre[b] + part[t] - own;               // exclusive within chunk
#pragma unroll
  for (int j = 0; j < 4; j++) {
    int idx = t * 4 + j;
    if (idx < CH) {
      offsets[b * CH + idx] = run;
      cursor[b * CH + idx] = run;
      run += cnt[idx];
    }
  }
  if (b == 0 && t == 0) offsets[M4] = 4 * NE;
}

// fill buckets: srcs (all hops), eids (valid where hop==0 only)
__global__ __launch_bounds__(256) void k_fill(
    const int* __restrict__ e0, const int* __restrict__ e1,
    const int* __restrict__ e2, const int* __restrict__ e3,
    int* __restrict__ cursor, int* __restrict__ srcs, int* __restrict__ eids) {
  const int h = blockIdx.y;
  const int* e = h == 0 ? e0 : h == 1 ? e1 : h == 2 ? e2 : e3;
  const int eid = blockIdx.x * 256 + threadIdx.x;
  const int src = e[eid];
  const int dst = e[NE + eid];
  const int pos = atomicAdd(&cursor[dst * 4 + h], 1);
  srcs[pos] = src;
  if (h == 0) eids[pos] = eid;
}

// ---------------------------------------------------------------------------
// One wave per dst node. All 4 hops' edges are contiguous (dst-major CSR);
// one merged loop unrolled x4 -> ~4 row-loads in flight per wave.
__global__ __launch_bounds__(256) void k_gather(
    const float* __restrict__ x0, const float* __restrict__ x1,
    const float* __restrict__ x2, const float* __restrict__ x3,
    const float* __restrict__ edge_attr, const float* __restrict__ eps,
    const int* __restrict__ offsets, const int* __restrict__ srcs,
    const int* __restrict__ eids, float* __restrict__ result) {
  const int dst  = blockIdx.x * 4 + (threadIdx.x >> 6);   // grid.x = NN/4 exact
  const int lane = threadIdx.x & 63;
  const int d    = lane * 2;

  const int4 ob = *reinterpret_cast<const int4*>(offsets + 4 * dst);
  const int o0 = ob.x, b1 = ob.y, b2 = ob.z, b3 = ob.w;
  const int o4 = offsets[4 * dst + 4];

  float2 s1 = *reinterpret_cast<const float2*>(eps + 1 * D + d);
  float2 s2 = *reinterpret_cast<const float2*>(eps + 2 * D + d);
  float2 s3 = *reinterpret_cast<const float2*>(eps + 3 * D + d);
  float2 s4 = *reinterpret_cast<const float2*>(eps + 4 * D + d);
  s1.x += 1.f; s1.y += 1.f; s2.x += 1.f; s2.y += 1.f;
  s3.x += 1.f; s3.y += 1.f; s4.x += 1.f; s4.y += 1.f;

  float2 e0v = *reinterpret_cast<const float2*>(eps + d);
  float2 xv  = *reinterpret_cast<const float2*>(x0 + (size_t)dst * D + d);
  float2 acc;
  acc.x = (1.f + e0v.x) * xv.x;
  acc.y = (1.f + e0v.y) * xv.y;

#define ACC_EDGE(JU, P) do {                                                  \
    const int ju_ = (JU);                                                     \
    const float* xp_ = (ju_ >= b3) ? x3 : (ju_ >= b2) ? x2                    \
                     : (ju_ >= b1) ? x1 : x0;                                 \
    float2 v_ = *reinterpret_cast<const float2*>(xp_ + (size_t)(P) * D + d);  \
    if (ju_ < b1) {                                                           \
      const int eid_ = eids[ju_];                                             \
      float2 a_ = *reinterpret_cast<const float2*>(edge_attr + (size_t)eid_ * D + d); \
      v_.x += a_.x; v_.y += a_.y;                                             \
    }                                                                         \
    const float2 sc_ = (ju_ >= b3) ? s4 : (ju_ >= b2) ? s3                    \
                     : (ju_ >= b1) ? s2 : s1;                                 \
    acc.x += sc_.x * fmaxf(v_.x, 0.f);                                        \
    acc.y += sc_.y * fmaxf(v_.y, 0.f);                                        \
  } while (0)

  int j = o0;
  for (; j + 4 <= o4; j += 4) {
    const int p0 = srcs[j + 0];
    const int p1 = srcs[j + 1];
    const int p2 = srcs[j + 2];
    const int p3 = srcs[j + 3];
    ACC_EDGE(j + 0, p0);
    ACC_EDGE(j + 1, p1);
    ACC_EDGE(j + 2, p2);
    ACC_EDGE(j + 3, p3);
  }
  for (; j < o4; ++j) {
    const int p = srcs[j];
    ACC_EDGE(j, p);
  }
#undef ACC_EDGE

  *reinterpret_cast<float2*>(result + (size_t)dst * D + d) = acc;
}

// ---------------------------------------------------------------------------
// GEMM1: C[N,256] = A[N,128] @ B[128,256]  (b1 cancels in BN1)
// Fused epilogue: per-column sum/sumsq -> atomics into sums1/sumsq1.
__global__ __launch_bounds__(512) void k_gemm1(const float* __restrict__ A,
                                               const float* __restrict__ B,
                                               float* __restrict__ C,
                                               float* __restrict__ sums1,
                                               float* __restrict__ sumsq1) {
  __shared__ float As[32][132];
  __shared__ float Bs[32][256];
  const int tid = threadIdx.x;
  const int tx = tid & 31, ty = tid >> 5;
  const int row0 = blockIdx.x * 128;

  float acc[8][8];
#pragma unroll
  for (int i = 0; i < 8; i++)
#pragma unroll
    for (int j = 0; j < 8; j++) acc[i][j] = 0.f;

  for (int k0 = 0; k0 < 128; k0 += 32) {
#pragma unroll
    for (int l = 0; l < 2; l++) {
      int f4 = tid + l * 512;
      int row = f4 >> 3, kq = f4 & 7;
      float4 v = make_float4(0.f, 0.f, 0.f, 0.f);
      if (row0 + row < NN)
        v = *reinterpret_cast<const float4*>(A + (size_t)(row0 + row) * 128 + k0 + kq * 4);
      As[kq * 4 + 0][row] = v.x; As[kq * 4 + 1][row] = v.y;
      As[kq * 4 + 2][row] = v.z; As[kq * 4 + 3][row] = v.w;
    }
#pragma unroll
    for (int l = 0; l < 4; l++) {
      int f4 = tid + l * 512;
      int kk = f4 >> 6, cq = f4 & 63;
      *reinterpret_cast<float4*>(&Bs[kk][cq * 4]) =
          *reinterpret_cast<const float4*>(B + (size_t)(k0 + kk) * 256 + cq * 4);
    }
    __syncthreads();
#pragma unroll
    for (int k = 0; k < 32; k++) {
      float a[8], b[8];
      *reinterpret_cast<float4*>(a)     = *reinterpret_cast<const float4*>(&As[k][ty * 8]);
      *reinterpret_cast<float4*>(a + 4) = *reinterpret_cast<const float4*>(&As[k][ty * 8 + 4]);
      *reinterpret_cast<float4*>(b)     = *reinterpret_cast<const float4*>(&Bs[k][tx * 4]);
      *reinterpret_cast<float4*>(b + 4) = *reinterpret_cast<const float4*>(&Bs[k][128 + tx * 4]);
#pragma unroll
      for (int i = 0; i < 8; i++)
#pragma unroll
        for (int j = 0; j < 8; j++) acc[i][j] = fmaf(a[i], b[j], acc[i][j]);
    }
    __syncthreads();
  }
#pragma unroll
  for (int i = 0; i < 8; i++) {
    int row = row0 + ty * 8 + i;
    if (row < NN) {
      *reinterpret_cast<float4*>(C + (size_t)row * 256 + tx * 4) =
          make_float4(acc[i][0], acc[i][1], acc[i][2], acc[i][3]);
      *reinterpret_cast<float4*>(C + (size_t)row * 256 + 128 + tx * 4) =
          make_float4(acc[i][4], acc[i][5], acc[i][6], acc[i][7]);
    }
  }
  // fused column stats (invalid rows have acc==0 -> contribute 0)
  float cs[8], cq[8];
#pragma unroll
  for (int j = 0; j < 8; j++) { cs[j] = 0.f; cq[j] = 0.f; }
#pragma unroll
  for (int i = 0; i < 8; i++)
#pragma unroll
    for (int j = 0; j < 8; j++) { cs[j] += acc[i][j]; cq[j] = fmaf(acc[i][j], acc[i][j], cq[j]); }
#pragma unroll
  for (int j = 0; j < 4; j++) {
    Bs[ty][tx * 4 + j]            = cs[j];
    Bs[16 + ty][tx * 4 + j]       = cq[j];
    Bs[ty][128 + tx * 4 + j]      = cs[4 + j];
    Bs[16 + ty][128 + tx * 4 + j] = cq[4 + j];
  }
  __syncthreads();
  if (tid < 256) {
    float s = 0.f, q = 0.f;
#pragma unroll
    for (int t = 0; t < 16; t++) { s += Bs[t][tid]; q += Bs[16 + t][tid]; }
    unsafeAtomicAdd(&sums1[tid], s);
    unsafeAtomicAdd(&sumsq1[tid], q);
  }
}

// ---------------------------------------------------------------------------
// GEMM2: C[N,128] = relu(bn1(t1))[N,256] @ W2[256,128]  (b2 cancels in BN2)
// Inlined BN1 scale/shift from raw sums; fused column stats for BN2.
__global__ __launch_bounds__(512) void k_gemm2(const float* __restrict__ A,
                                               const float* __restrict__ B,
                                               const float* __restrict__ sums1,
                                               const float* __restrict__ sumsq1,
                                               const float* __restrict__ bn1_g,
                                               const float* __restrict__ bn1_b,
                                               float* __restrict__ C,
                                               float* __restrict__ sums2,
                                               float* __restrict__ sumsq2) {
  __shared__ float As[32][132];
  __shared__ float Bs[32][128];
  __shared__ float s1s[256], s1h[256];
  const int tid = threadIdx.x;
  const int tx = tid & 31, ty = tid >> 5;
  const int row0 = blockIdx.x * 128;

  if (tid < 256) {
    float mean = sums1[tid] * (1.f / NN);
    float var  = sumsq1[tid] * (1.f / NN) - mean * mean;
    float rs   = rsqrtf(var + BN_EPS);
    float s    = bn1_g[tid] * rs;
    s1s[tid] = s;
    s1h[tid] = bn1_b[tid] - mean * s;
  }
  __syncthreads();

  float acc[8][4];
#pragma unroll
  for (int i = 0; i < 8; i++)
#pragma unroll
    for (int j = 0; j < 4; j++) acc[i][j] = 0.f;

  for (int k0 = 0; k0 < 256; k0 += 32) {
#pragma unroll
    for (int l = 0; l < 2; l++) {
      int f4 = tid + l * 512;
      int row = f4 >> 3, kq = f4 & 7;
      float4 v = make_float4(0.f, 0.f, 0.f, 0.f);
      if (row0 + row < NN)
        v = *reinterpret_cast<const float4*>(A + (size_t)(row0 + row) * 256 + k0 + kq * 4);
      float4 s  = *reinterpret_cast<const float4*>(&s1s[k0 + kq * 4]);
      float4 hh = *reinterpret_cast<const float4*>(&s1h[k0 + kq * 4]);
      v.x = fmaxf(fmaf(s.x, v.x, hh.x), 0.f);
      v.y = fmaxf(fmaf(s.y, v.y, hh.y), 0.f);
      v.z = fmaxf(fmaf(s.z, v.z, hh.z), 0.f);
      v.w = fmaxf(fmaf(s.w, v.w, hh.w), 0.f);
      As[kq * 4 + 0][row] = v.x; As[kq * 4 + 1][row] = v.y;
      As[kq * 4 + 2][row] = v.z; As[kq * 4 + 3][row] = v.w;
    }
#pragma unroll
    for (int l = 0; l < 2; l++) {
      int f4 = tid + l * 512;
      int kk = f4 >> 5, cq = f4 & 31;
      *reinterpret_cast<float4*>(&Bs[kk][cq * 4]) =
          *reinterpret_cast<const float4*>(B + (size_t)(k0 + kk) * 128 + cq * 4);
    }
    __syncthreads();
#pragma unroll
    for (int k = 0; k < 32; k++) {
      float a[8], b[4];
      *reinterpret_cast<float4*>(a)     = *reinterpret_cast<const float4*>(&As[k][ty * 8]);
      *reinterpret_cast<float4*>(a + 4) = *reinterpret_cast<const float4*>(&As[k][ty * 8 + 4]);
      *reinterpret_cast<float4*>(b)     = *reinterpret_cast<const float4*>(&Bs[k][tx * 4]);
#pragma unroll
      for (int i = 0; i < 8; i++)
#pragma unroll
        for (int j = 0; j < 4; j++) acc[i][j] = fmaf(a[i], b[j], acc[i][j]);
    }
    __syncthreads();
  }
#pragma unroll
  for (int i = 0; i < 8; i++) {
    int row = row0 + ty * 8 + i;
    if (row < NN)
      *reinterpret_cast<float4*>(C + (size_t)row * 128 + tx * 4) =
          make_float4(acc[i][0], acc[i][1], acc[i][2], acc[i][3]);
  }
  // fused column stats for BN2
  float cs[4], cq[4];
#pragma unroll
  for (int j = 0; j < 4; j++) { cs[j] = 0.f; cq[j] = 0.f; }
#pragma unroll
  for (int i = 0; i < 8; i++)
#pragma unroll
    for (int j = 0; j < 4; j++) { cs[j] += acc[i][j]; cq[j] = fmaf(acc[i][j], acc[i][j], cq[j]); }
#pragma unroll
  for (int j = 0; j < 4; j++) {
    Bs[ty][tx * 4 + j]      = cs[j];
    Bs[16 + ty][tx * 4 + j] = cq[j];
  }
  __syncthreads();
  if (tid < 128) {
    float s = 0.f, q = 0.f;
#pragma unroll
    for (int t = 0; t < 16; t++) { s += Bs[t][tid]; q += Bs[16 + t][tid]; }
    unsafeAtomicAdd(&sums2[tid], s);
    unsafeAtomicAdd(&sumsq2[tid], q);
  }
}

// ---------------------------------------------------------------------------
// Column stats of relu(bn2(t2)) -> sums3/sumsq3. BN2 scale/shift inlined.
__global__ __launch_bounds__(256) void k_colstats3(const float* __restrict__ X,
                                                   const float* __restrict__ sums2,
                                                   const float* __restrict__ sumsq2,
                                                   const float* __restrict__ bn2_g,
                                                   const float* __restrict__ bn2_b,
                                                   float* __restrict__ sums3,
                                                   float* __restrict__ sumsq3) {
  const long total = (long)NN * 128;
  const long stride = (long)gridDim.x * 256;
  const long start = (long)blockIdx.x * 256 + threadIdx.x;
  const int c = (int)(start & 127);
  float mean = sums2[c] * (1.f / NN);
  float var  = sumsq2[c] * (1.f / NN) - mean * mean;
  float rs   = rsqrtf(var + BN_EPS);
  float scale = bn2_g[c] * rs;
  float shiftv = bn2_b[c] - mean * scale;
  float s = 0.f, q = 0.f;
  for (long idx = start; idx < total; idx += stride) {
    float v = fmaxf(fmaf(scale, X[idx], shiftv), 0.f);
    s += v;
    q = fmaf(v, v, q);
  }
  unsafeAtomicAdd(&sums3[c], s);
  unsafeAtomicAdd(&sumsq3[c], q);
}

// out = relu(bn3(relu(bn2(t2)))), in place on d_out; BN2/BN3 inlined.
__global__ __launch_bounds__(256) void k_final(float* __restrict__ t2,
                                               const float* __restrict__ sums2,
                                               const float* __restrict__ sumsq2,
                                               const float* __restrict__ bn2_g,
                                               const float* __restrict__ bn2_b,
                                               const float* __restrict__ sums3,
                                               const float* __restrict__ sumsq3,
                                               const float* __restrict__ bn3_g,
                                               const float* __restrict__ bn3_b) {
  int i4 = blockIdx.x * 256 + threadIdx.x;
  if (i4 >= NN * D / 4) return;
  int d = (i4 & 31) * 4;
  float4 v = reinterpret_cast<float4*>(t2)[i4];
  float o[4];
  float* vv = reinterpret_cast<float*>(&v);
#pragma unroll
  for (int j = 0; j < 4; j++) {
    int c = d + j;
    float m2 = sums2[c] * (1.f / NN);
    float va2 = sumsq2[c] * (1.f / NN) - m2 * m2;
    float r2 = rsqrtf(va2 + BN_EPS);
    float a2 = bn2_g[c] * r2;
    float h2 = bn2_b[c] - m2 * a2;
    float m3 = sums3[c] * (1.f / NN);
    float va3 = sumsq3[c] * (1.f / NN) - m3 * m3;
    float r3 = rsqrtf(va3 + BN_EPS);
    float a3 = bn3_g[c] * r3;
    float h3 = bn3_b[c] - m3 * a3;
    o[j] = fmaxf(fmaf(a3, fmaxf(fmaf(a2, vv[j], h2), 0.f), h3), 0.f);
  }
  reinterpret_cast<float4*>(t2)[i4] = make_float4(o[0], o[1], o[2], o[3]);
}

// ---------------------------------------------------------------------------
extern "C" void kernel_launch(void* const* d_in, const int* in_sizes, int n_in,
                              void* d_out, int out_size, void* d_ws, size_t ws_size,
                              hipStream_t stream) {
  const float* x0 = (const float*)d_in[0];
  const float* x1 = (const float*)d_in[1];
  const float* x2 = (const float*)d_in[2];
  const float* x3 = (const float*)d_in[3];
  const float* edge_attr = (const float*)d_in[4];
  const int* e0 = (const int*)d_in[5];
  const int* e1 = (const int*)d_in[6];
  const int* e2 = (const int*)d_in[7];
  const int* e3 = (const int*)d_in[8];
  const float* W1 = (const float*)d_in[9];
  // d_in[10] = b1 (cancels in BN1)
  const float* bn1_g = (const float*)d_in[11];
  const float* bn1_b = (const float*)d_in[12];
  const float* W2 = (const float*)d_in[13];
  // d_in[14] = b2 (cancels in BN2)
  const float* bn2_g = (const float*)d_in[15];
  const float* bn2_b = (const float*)d_in[16];
  const float* bn3_g = (const float*)d_in[17];
  const float* bn3_b = (const float*)d_in[18];
  const float* eps = (const float*)d_in[19];

  float* ws = (float*)d_ws;
  float* result = ws;                               // N*128 floats
  float* t1 = ws + (size_t)NN * D;                  // N*256 floats

  // CSR arrays alias the t1 region (dead until k_gemm1 writes t1)
  int* counts  = (int*)t1;                          // 400000
  int* offsets = counts + M4;                       // 400001
  int* cursor  = offsets + M4 + 1;                  // 400000
  int* bsum    = cursor + M4;                       // 400
  int* bpre    = bsum + NB;                         // 400
  int* srcs    = bpre + NB;                         // 3200000
  int* eids    = srcs + 4 * NE;                     // 3200000 (hop-0 entries valid)

  float* stats = t1 + (size_t)NN * 256;
  float* sums1  = stats;           // 256
  float* sumsq1 = sums1 + 256;     // 256
  float* sums2  = sumsq1 + 256;    // 128
  float* sumsq2 = sums2 + 128;     // 128
  float* sums3  = sumsq2 + 128;    // 128
  float* sumsq3 = sums3 + 128;     // 128
  float* t2 = (float*)d_out;                        // reuse output as t2

  hipMemsetAsync(counts, 0, M4 * sizeof(int), stream);
  hipMemsetAsync(stats, 0, 1024 * sizeof(float), stream);

  // CSR build (dst-major buckets)
  k_count<<<dim3(NE / 256, 4), 256, 0, stream>>>(e0, e1, e2, e3, counts);
  k_scanA<<<NB, 256, 0, stream>>>(counts, bsum);
  k_scanB<<<1, 512, 0, stream>>>(bsum, bpre);
  k_scanC<<<NB, 256, 0, stream>>>(counts, bpre, offsets, cursor);
  k_fill<<<dim3(NE / 256, 4), 256, 0, stream>>>(e0, e1, e2, e3, cursor, srcs, eids);

  // merged-loop register aggregation, one wave per node
  k_gather<<<NN / 4, 256, 0, stream>>>(x0, x1, x2, x3, edge_attr, eps,
                                       offsets, srcs, eids, result);

  // MLP + BNs (stats fused into GEMM epilogues, bnfinal inlined in consumers)
  k_gemm1<<<(NN + 127) / 128, 512, 0, stream>>>(result, W1, t1, sums1, sumsq1);
  k_gemm2<<<(NN + 127) / 128, 512, 0, stream>>>(t1, W2, sums1, sumsq1, bn1_g, bn1_b,
                                                t2, sums2, sumsq2);
  k_colstats3<<<512, 256, 0, stream>>>(t2, sums2, sumsq2, bn2_g, bn2_b, sums3, sumsq3);
  k_final<<<NN * D / 4 / 256, 256, 0, stream>>>(t2, sums2, sumsq2, bn2_g, bn2_b,
                                                sums3, sumsq3, bn3_g, bn3_b);
}

// Round 4
// 883.138 us; speedup vs baseline: 3.4147x; 1.0257x over previous
//
#include <hip/hip_runtime.h>
#include <cstdint>
#include <cstddef>

#define NN 100000
#define D 128
#define NE 800000
#define BN_EPS 1e-5f

#define M4 (4 * NN)     // total buckets (dst-major: dst*4 + hop)
#define CH 1000         // scan chunk
#define NB 400          // M4 / CH

// ---------------------------------------------------------------------------
// CSR build: in-degree count per (dst, hop)
__global__ __launch_bounds__(256) void k_count(
    const int* __restrict__ e0, const int* __restrict__ e1,
    const int* __restrict__ e2, const int* __restrict__ e3,
    int* __restrict__ counts) {
  const int h = blockIdx.y;
  const int* e = h == 0 ? e0 : h == 1 ? e1 : h == 2 ? e2 : e3;
  const int eid = blockIdx.x * 256 + threadIdx.x;   // grid.x = NE/256 exact
  const int dst = e[NE + eid];
  atomicAdd(&counts[dst * 4 + h], 1);
}

// chunk sums
__global__ __launch_bounds__(256) void k_scanA(const int* __restrict__ counts,
                                               int* __restrict__ bsum) {
  __shared__ int red[256];
  const int b = blockIdx.x, t = threadIdx.x;
  int s = 0;
  for (int i = t; i < CH; i += 256) s += counts[b * CH + i];
  red[t] = s; __syncthreads();
  for (int off = 128; off > 0; off >>= 1) {
    if (t < off) red[t] += red[t + off];
    __syncthreads();
  }
  if (t == 0) bsum[b] = red[0];
}

// exclusive scan of chunk sums (NB=400 <= 512)
__global__ __launch_bounds__(512) void k_scanB(const int* __restrict__ bsum,
                                               int* __restrict__ bpre) {
  __shared__ int s[512];
  const int t = threadIdx.x;
  const int v = (t < NB) ? bsum[t] : 0;
  s[t] = v; __syncthreads();
  for (int off = 1; off < 512; off <<= 1) {
    int x = s[t];
    if (t >= off) x += s[t - off];
    __syncthreads(); s[t] = x; __syncthreads();
  }
  if (t < NB) bpre[t] = s[t] - v;
}

// per-chunk exclusive scan -> offsets (and cursor copy for fill)
__global__ __launch_bounds__(256) void k_scanC(const int* __restrict__ counts,
                                               const int* __restrict__ bpre,
                                               int* __restrict__ offsets,
                                               int* __restrict__ cursor) {
  __shared__ int cnt[CH];
  __shared__ int part[256];
  const int b = blockIdx.x, t = threadIdx.x;
  for (int i = t; i < CH; i += 256) cnt[i] = counts[b * CH + i];
  __syncthreads();
  int own = 0;
#pragma unroll
  for (int j = 0; j < 4; j++) {
    int idx = t * 4 + j;
    if (idx < CH) own += cnt[idx];
  }
  part[t] = own; __syncthreads();
  for (int off = 1; off < 256; off <<= 1) {        // inclusive scan
    int x = part[t];
    if (t >= off) x += part[t - off];
    __syncthreads(); part[t] = x; __syncthreads();
  }
  int run = bpre[b] + part[t] - own;               // exclusive within chunk
#pragma unroll
  for (int j = 0; j < 4; j++) {
    int idx = t * 4 + j;
    if (idx < CH) {
      offsets[b * CH + idx] = run;
      cursor[b * CH + idx] = run;
      run += cnt[idx];
    }
  }
  if (b == 0 && t == 0) offsets[M4] = 4 * NE;
}

// fill buckets: srcs (all hops), eids (valid where hop==0 only)
__global__ __launch_bounds__(256) void k_fill(
    const int* __restrict__ e0, const int* __restrict__ e1,
    const int* __restrict__ e2, const int* __restrict__ e3,
    int* __restrict__ cursor, int* __restrict__ srcs, int* __restrict__ eids) {
  const int h = blockIdx.y;
  const int* e = h == 0 ? e0 : h == 1 ? e1 : h == 2 ? e2 : e3;
  const int eid = blockIdx.x * 256 + threadIdx.x;
  const int src = e[eid];
  const int dst = e[NE + eid];
  const int pos = atomicAdd(&cursor[dst * 4 + h], 1);
  srcs[pos] = src;
  if (h == 0) eids[pos] = eid;
}

// ---------------------------------------------------------------------------
// One wave per dst node. dst-major CSR: 4 hop sub-ranges are contiguous and
// wave-uniform -> 4 select-free inner loops, per-hop raw accumulators,
// scales applied once at the end. Unrolled for ILP.
__global__ __launch_bounds__(256) void k_gather(
    const float* __restrict__ x0, const float* __restrict__ x1,
    const float* __restrict__ x2, const float* __restrict__ x3,
    const float* __restrict__ edge_attr, const float* __restrict__ eps,
    const int* __restrict__ offsets, const int* __restrict__ srcs,
    const int* __restrict__ eids, float* __restrict__ result) {
  const int dst  = blockIdx.x * 4 + (threadIdx.x >> 6);   // grid.x = NN/4 exact
  const int lane = threadIdx.x & 63;
  const int d    = lane * 2;

  const int4 ob = *reinterpret_cast<const int4*>(offsets + 4 * dst);
  const int o0 = ob.x, b1 = ob.y, b2 = ob.z, b3 = ob.w;
  const int o4 = offsets[4 * dst + 4];

  float2 h0 = make_float2(0.f, 0.f);
  float2 h1 = make_float2(0.f, 0.f);
  float2 h2 = make_float2(0.f, 0.f);
  float2 h3 = make_float2(0.f, 0.f);

  // ---- hop 0: x0[src] + edge_attr[eid], unroll x2 (2 loads per edge)
  {
    int j = o0;
    for (; j + 2 <= b1; j += 2) {
      const int p0 = srcs[j],     p1 = srcs[j + 1];
      const int q0 = eids[j],     q1 = eids[j + 1];
      float2 v0 = *reinterpret_cast<const float2*>(x0 + p0 * D + d);
      float2 w0 = *reinterpret_cast<const float2*>(edge_attr + (size_t)q0 * D + d);
      float2 v1 = *reinterpret_cast<const float2*>(x0 + p1 * D + d);
      float2 w1 = *reinterpret_cast<const float2*>(edge_attr + (size_t)q1 * D + d);
      h0.x += fmaxf(v0.x + w0.x, 0.f); h0.y += fmaxf(v0.y + w0.y, 0.f);
      h0.x += fmaxf(v1.x + w1.x, 0.f); h0.y += fmaxf(v1.y + w1.y, 0.f);
    }
    if (j < b1) {
      const int p = srcs[j];
      const int q = eids[j];
      float2 v = *reinterpret_cast<const float2*>(x0 + p * D + d);
      float2 w = *reinterpret_cast<const float2*>(edge_attr + (size_t)q * D + d);
      h0.x += fmaxf(v.x + w.x, 0.f); h0.y += fmaxf(v.y + w.y, 0.f);
    }
  }

#define HOP_LOOP(XP, ACC, BEG, END) do {                                       \
    int j_ = (BEG);                                                            \
    for (; j_ + 4 <= (END); j_ += 4) {                                         \
      const int p0_ = srcs[j_], p1_ = srcs[j_ + 1];                            \
      const int p2_ = srcs[j_ + 2], p3_ = srcs[j_ + 3];                        \
      float2 v0_ = *reinterpret_cast<const float2*>((XP) + p0_ * D + d);       \
      float2 v1_ = *reinterpret_cast<const float2*>((XP) + p1_ * D + d);       \
      float2 v2_ = *reinterpret_cast<const float2*>((XP) + p2_ * D + d);       \
      float2 v3_ = *reinterpret_cast<const float2*>((XP) + p3_ * D + d);       \
      ACC.x += fmaxf(v0_.x, 0.f); ACC.y += fmaxf(v0_.y, 0.f);                  \
      ACC.x += fmaxf(v1_.x, 0.f); ACC.y += fmaxf(v1_.y, 0.f);                  \
      ACC.x += fmaxf(v2_.x, 0.f); ACC.y += fmaxf(v2_.y, 0.f);                  \
      ACC.x += fmaxf(v3_.x, 0.f); ACC.y += fmaxf(v3_.y, 0.f);                  \
    }                                                                          \
    for (; j_ < (END); ++j_) {                                                 \
      const int p_ = srcs[j_];                                                 \
      float2 v_ = *reinterpret_cast<const float2*>((XP) + p_ * D + d);         \
      ACC.x += fmaxf(v_.x, 0.f); ACC.y += fmaxf(v_.y, 0.f);                    \
    }                                                                          \
  } while (0)

  HOP_LOOP(x1, h1, b1, b2);
  HOP_LOOP(x2, h2, b2, b3);
  HOP_LOOP(x3, h3, b3, o4);
#undef HOP_LOOP

  float2 e0v = *reinterpret_cast<const float2*>(eps + d);
  float2 s1 = *reinterpret_cast<const float2*>(eps + 1 * D + d);
  float2 s2 = *reinterpret_cast<const float2*>(eps + 2 * D + d);
  float2 s3 = *reinterpret_cast<const float2*>(eps + 3 * D + d);
  float2 s4 = *reinterpret_cast<const float2*>(eps + 4 * D + d);
  float2 xv = *reinterpret_cast<const float2*>(x0 + dst * D + d);

  float2 acc;
  acc.x = (1.f + e0v.x) * xv.x + (1.f + s1.x) * h0.x + (1.f + s2.x) * h1.x
        + (1.f + s3.x) * h2.x + (1.f + s4.x) * h3.x;
  acc.y = (1.f + e0v.y) * xv.y + (1.f + s1.y) * h0.y + (1.f + s2.y) * h1.y
        + (1.f + s3.y) * h2.y + (1.f + s4.y) * h3.y;

  *reinterpret_cast<float2*>(result + dst * D + d) = acc;
}

// ---------------------------------------------------------------------------
// GEMM1: C[N,256] = A[N,128] @ B[128,256]  (b1 cancels in BN1)
// Fused epilogue: per-column sum/sumsq -> atomics into sums1/sumsq1.
__global__ __launch_bounds__(512) void k_gemm1(const float* __restrict__ A,
                                               const float* __restrict__ B,
                                               float* __restrict__ C,
                                               float* __restrict__ sums1,
                                               float* __restrict__ sumsq1) {
  __shared__ float As[32][132];
  __shared__ float Bs[32][256];
  const int tid = threadIdx.x;
  const int tx = tid & 31, ty = tid >> 5;
  const int row0 = blockIdx.x * 128;

  float acc[8][8];
#pragma unroll
  for (int i = 0; i < 8; i++)
#pragma unroll
    for (int j = 0; j < 8; j++) acc[i][j] = 0.f;

  for (int k0 = 0; k0 < 128; k0 += 32) {
#pragma unroll
    for (int l = 0; l < 2; l++) {
      int f4 = tid + l * 512;
      int row = f4 >> 3, kq = f4 & 7;
      float4 v = make_float4(0.f, 0.f, 0.f, 0.f);
      if (row0 + row < NN)
        v = *reinterpret_cast<const float4*>(A + (size_t)(row0 + row) * 128 + k0 + kq * 4);
      As[kq * 4 + 0][row] = v.x; As[kq * 4 + 1][row] = v.y;
      As[kq * 4 + 2][row] = v.z; As[kq * 4 + 3][row] = v.w;
    }
#pragma unroll
    for (int l = 0; l < 4; l++) {
      int f4 = tid + l * 512;
      int kk = f4 >> 6, cq = f4 & 63;
      *reinterpret_cast<float4*>(&Bs[kk][cq * 4]) =
          *reinterpret_cast<const float4*>(B + (size_t)(k0 + kk) * 256 + cq * 4);
    }
    __syncthreads();
#pragma unroll
    for (int k = 0; k < 32; k++) {
      float a[8], b[8];
      *reinterpret_cast<float4*>(a)     = *reinterpret_cast<const float4*>(&As[k][ty * 8]);
      *reinterpret_cast<float4*>(a + 4) = *reinterpret_cast<const float4*>(&As[k][ty * 8 + 4]);
      *reinterpret_cast<float4*>(b)     = *reinterpret_cast<const float4*>(&Bs[k][tx * 4]);
      *reinterpret_cast<float4*>(b + 4) = *reinterpret_cast<const float4*>(&Bs[k][128 + tx * 4]);
#pragma unroll
      for (int i = 0; i < 8; i++)
#pragma unroll
        for (int j = 0; j < 8; j++) acc[i][j] = fmaf(a[i], b[j], acc[i][j]);
    }
    __syncthreads();
  }
#pragma unroll
  for (int i = 0; i < 8; i++) {
    int row = row0 + ty * 8 + i;
    if (row < NN) {
      *reinterpret_cast<float4*>(C + (size_t)row * 256 + tx * 4) =
          make_float4(acc[i][0], acc[i][1], acc[i][2], acc[i][3]);
      *reinterpret_cast<float4*>(C + (size_t)row * 256 + 128 + tx * 4) =
          make_float4(acc[i][4], acc[i][5], acc[i][6], acc[i][7]);
    }
  }
  // fused column stats (invalid rows have acc==0 -> contribute 0)
  float cs[8], cq[8];
#pragma unroll
  for (int j = 0; j < 8; j++) { cs[j] = 0.f; cq[j] = 0.f; }
#pragma unroll
  for (int i = 0; i < 8; i++)
#pragma unroll
    for (int j = 0; j < 8; j++) { cs[j] += acc[i][j]; cq[j] = fmaf(acc[i][j], acc[i][j], cq[j]); }
#pragma unroll
  for (int j = 0; j < 4; j++) {
    Bs[ty][tx * 4 + j]            = cs[j];
    Bs[16 + ty][tx * 4 + j]       = cq[j];
    Bs[ty][128 + tx * 4 + j]      = cs[4 + j];
    Bs[16 + ty][128 + tx * 4 + j] = cq[4 + j];
  }
  __syncthreads();
  if (tid < 256) {
    float s = 0.f, q = 0.f;
#pragma unroll
    for (int t = 0; t < 16; t++) { s += Bs[t][tid]; q += Bs[16 + t][tid]; }
    unsafeAtomicAdd(&sums1[tid], s);
    unsafeAtomicAdd(&sumsq1[tid], q);
  }
}

// ---------------------------------------------------------------------------
// GEMM2: C[N,128] = relu(bn1(t1))[N,256] @ W2[256,128]  (b2 cancels in BN2)
// Inlined BN1 scale/shift from raw sums; fused column stats for BN2.
__global__ __launch_bounds__(512) void k_gemm2(const float* __restrict__ A,
                                               const float* __restrict__ B,
                                               const float* __restrict__ sums1,
                                               const float* __restrict__ sumsq1,
                                               const float* __restrict__ bn1_g,
                                               const float* __restrict__ bn1_b,
                                               float* __restrict__ C,
                                               float* __restrict__ sums2,
                                               float* __restrict__ sumsq2) {
  __shared__ float As[32][132];
  __shared__ float Bs[32][128];
  __shared__ float s1s[256], s1h[256];
  const int tid = threadIdx.x;
  const int tx = tid & 31, ty = tid >> 5;
  const int row0 = blockIdx.x * 128;

  if (tid < 256) {
    float mean = sums1[tid] * (1.f / NN);
    float var  = sumsq1[tid] * (1.f / NN) - mean * mean;
    float rs   = rsqrtf(var + BN_EPS);
    float s    = bn1_g[tid] * rs;
    s1s[tid] = s;
    s1h[tid] = bn1_b[tid] - mean * s;
  }
  __syncthreads();

  float acc[8][4];
#pragma unroll
  for (int i = 0; i < 8; i++)
#pragma unroll
    for (int j = 0; j < 4; j++) acc[i][j] = 0.f;

  for (int k0 = 0; k0 < 256; k0 += 32) {
#pragma unroll
    for (int l = 0; l < 2; l++) {
      int f4 = tid + l * 512;
      int row = f4 >> 3, kq = f4 & 7;
      float4 v = make_float4(0.f, 0.f, 0.f, 0.f);
      if (row0 + row < NN)
        v = *reinterpret_cast<const float4*>(A + (size_t)(row0 + row) * 256 + k0 + kq * 4);
      float4 s  = *reinterpret_cast<const float4*>(&s1s[k0 + kq * 4]);
      float4 hh = *reinterpret_cast<const float4*>(&s1h[k0 + kq * 4]);
      v.x = fmaxf(fmaf(s.x, v.x, hh.x), 0.f);
      v.y = fmaxf(fmaf(s.y, v.y, hh.y), 0.f);
      v.z = fmaxf(fmaf(s.z, v.z, hh.z), 0.f);
      v.w = fmaxf(fmaf(s.w, v.w, hh.w), 0.f);
      As[kq * 4 + 0][row] = v.x; As[kq * 4 + 1][row] = v.y;
      As[kq * 4 + 2][row] = v.z; As[kq * 4 + 3][row] = v.w;
    }
#pragma unroll
    for (int l = 0; l < 2; l++) {
      int f4 = tid + l * 512;
      int kk = f4 >> 5, cq = f4 & 31;
      *reinterpret_cast<float4*>(&Bs[kk][cq * 4]) =
          *reinterpret_cast<const float4*>(B + (size_t)(k0 + kk) * 128 + cq * 4);
    }
    __syncthreads();
#pragma unroll
    for (int k = 0; k < 32; k++) {
      float a[8], b[4];
      *reinterpret_cast<float4*>(a)     = *reinterpret_cast<const float4*>(&As[k][ty * 8]);
      *reinterpret_cast<float4*>(a + 4) = *reinterpret_cast<const float4*>(&As[k][ty * 8 + 4]);
      *reinterpret_cast<float4*>(b)     = *reinterpret_cast<const float4*>(&Bs[k][tx * 4]);
#pragma unroll
      for (int i = 0; i < 8; i++)
#pragma unroll
        for (int j = 0; j < 4; j++) acc[i][j] = fmaf(a[i], b[j], acc[i][j]);
    }
    __syncthreads();
  }
#pragma unroll
  for (int i = 0; i < 8; i++) {
    int row = row0 + ty * 8 + i;
    if (row < NN)
      *reinterpret_cast<float4*>(C + (size_t)row * 128 + tx * 4) =
          make_float4(acc[i][0], acc[i][1], acc[i][2], acc[i][3]);
  }
  // fused column stats for BN2
  float cs[4], cq[4];
#pragma unroll
  for (int j = 0; j < 4; j++) { cs[j] = 0.f; cq[j] = 0.f; }
#pragma unroll
  for (int i = 0; i < 8; i++)
#pragma unroll
    for (int j = 0; j < 4; j++) { cs[j] += acc[i][j]; cq[j] = fmaf(acc[i][j], acc[i][j], cq[j]); }
#pragma unroll
  for (int j = 0; j < 4; j++) {
    Bs[ty][tx * 4 + j]      = cs[j];
    Bs[16 + ty][tx * 4 + j] = cq[j];
  }
  __syncthreads();
  if (tid < 128) {
    float s = 0.f, q = 0.f;
#pragma unroll
    for (int t = 0; t < 16; t++) { s += Bs[t][tid]; q += Bs[16 + t][tid]; }
    unsafeAtomicAdd(&sums2[tid], s);
    unsafeAtomicAdd(&sumsq2[tid], q);
  }
}

// ---------------------------------------------------------------------------
// Column stats of relu(bn2(t2)) -> sums3/sumsq3. BN2 scale/shift inlined.
__global__ __launch_bounds__(256) void k_colstats3(const float* __restrict__ X,
                                                   const float* __restrict__ sums2,
                                                   const float* __restrict__ sumsq2,
                                                   const float* __restrict__ bn2_g,
                                                   const float* __restrict__ bn2_b,
                                                   float* __restrict__ sums3,
                                                   float* __restrict__ sumsq3) {
  const long total = (long)NN * 128;
  const long stride = (long)gridDim.x * 256;
  const long start = (long)blockIdx.x * 256 + threadIdx.x;
  const int c = (int)(start & 127);
  float mean = sums2[c] * (1.f / NN);
  float var  = sumsq2[c] * (1.f / NN) - mean * mean;
  float rs   = rsqrtf(var + BN_EPS);
  float scale = bn2_g[c] * rs;
  float shiftv = bn2_b[c] - mean * scale;
  float s = 0.f, q = 0.f;
  for (long idx = start; idx < total; idx += stride) {
    float v = fmaxf(fmaf(scale, X[idx], shiftv), 0.f);
    s += v;
    q = fmaf(v, v, q);
  }
  unsafeAtomicAdd(&sums3[c], s);
  unsafeAtomicAdd(&sumsq3[c], q);
}

// out = relu(bn3(relu(bn2(t2)))), in place on d_out; BN2/BN3 inlined.
__global__ __launch_bounds__(256) void k_final(float* __restrict__ t2,
                                               const float* __restrict__ sums2,
                                               const float* __restrict__ sumsq2,
                                               const float* __restrict__ bn2_g,
                                               const float* __restrict__ bn2_b,
                                               const float* __restrict__ sums3,
                                               const float* __restrict__ sumsq3,
                                               const float* __restrict__ bn3_g,
                                               const float* __restrict__ bn3_b) {
  int i4 = blockIdx.x * 256 + threadIdx.x;
  if (i4 >= NN * D / 4) return;
  int d = (i4 & 31) * 4;
  float4 v = reinterpret_cast<float4*>(t2)[i4];
  float o[4];
  float* vv = reinterpret_cast<float*>(&v);
#pragma unroll
  for (int j = 0; j < 4; j++) {
    int c = d + j;
    float m2 = sums2[c] * (1.f / NN);
    float va2 = sumsq2[c] * (1.f / NN) - m2 * m2;
    float r2 = rsqrtf(va2 + BN_EPS);
    float a2 = bn2_g[c] * r2;
    float h2 = bn2_b[c] - m2 * a2;
    float m3 = sums3[c] * (1.f / NN);
    float va3 = sumsq3[c] * (1.f / NN) - m3 * m3;
    float r3 = rsqrtf(va3 + BN_EPS);
    float a3 = bn3_g[c] * r3;
    float h3 = bn3_b[c] - m3 * a3;
    o[j] = fmaxf(fmaf(a3, fmaxf(fmaf(a2, vv[j], h2), 0.f), h3), 0.f);
  }
  reinterpret_cast<float4*>(t2)[i4] = make_float4(o[0], o[1], o[2], o[3]);
}

// ---------------------------------------------------------------------------
extern "C" void kernel_launch(void* const* d_in, const int* in_sizes, int n_in,
                              void* d_out, int out_size, void* d_ws, size_t ws_size,
                              hipStream_t stream) {
  const float* x0 = (const float*)d_in[0];
  const float* x1 = (const float*)d_in[1];
  const float* x2 = (const float*)d_in[2];
  const float* x3 = (const float*)d_in[3];
  const float* edge_attr = (const float*)d_in[4];
  const int* e0 = (const int*)d_in[5];
  const int* e1 = (const int*)d_in[6];
  const int* e2 = (const int*)d_in[7];
  const int* e3 = (const int*)d_in[8];
  const float* W1 = (const float*)d_in[9];
  // d_in[10] = b1 (cancels in BN1)
  const float* bn1_g = (const float*)d_in[11];
  const float* bn1_b = (const float*)d_in[12];
  const float* W2 = (const float*)d_in[13];
  // d_in[14] = b2 (cancels in BN2)
  const float* bn2_g = (const float*)d_in[15];
  const float* bn2_b = (const float*)d_in[16];
  const float* bn3_g = (const float*)d_in[17];
  const float* bn3_b = (const float*)d_in[18];
  const float* eps = (const float*)d_in[19];

  float* ws = (float*)d_ws;
  float* result = ws;                               // N*128 floats
  float* t1 = ws + (size_t)NN * D;                  // N*256 floats

  // CSR arrays alias the t1 region (dead until k_gemm1 writes t1)
  int* counts  = (int*)t1;                          // 400000
  int* offsets = counts + M4;                       // 400001
  int* cursor  = offsets + M4 + 1;                  // 400000
  int* bsum    = cursor + M4;                       // 400
  int* bpre    = bsum + NB;                         // 400
  int* srcs    = bpre + NB;                         // 3200000
  int* eids    = srcs + 4 * NE;                     // 3200000 (hop-0 entries valid)

  float* stats = t1 + (size_t)NN * 256;
  float* sums1  = stats;           // 256
  float* sumsq1 = sums1 + 256;     // 256
  float* sums2  = sumsq1 + 256;    // 128
  float* sumsq2 = sums2 + 128;     // 128
  float* sums3  = sumsq2 + 128;    // 128
  float* sumsq3 = sums3 + 128;     // 128
  float* t2 = (float*)d_out;                        // reuse output as t2

  hipMemsetAsync(counts, 0, M4 * sizeof(int), stream);
  hipMemsetAsync(stats, 0, 1024 * sizeof(float), stream);

  // CSR build (dst-major buckets)
  k_count<<<dim3(NE / 256, 4), 256, 0, stream>>>(e0, e1, e2, e3, counts);
  k_scanA<<<NB, 256, 0, stream>>>(counts, bsum);
  k_scanB<<<1, 512, 0, stream>>>(bsum, bpre);
  k_scanC<<<NB, 256, 0, stream>>>(counts, bpre, offsets, cursor);
  k_fill<<<dim3(NE / 256, 4), 256, 0, stream>>>(e0, e1, e2, e3, cursor, srcs, eids);

  // select-free per-hop loops, one wave per node
  k_gather<<<NN / 4, 256, 0, stream>>>(x0, x1, x2, x3, edge_attr, eps,
                                       offsets, srcs, eids, result);

  // MLP + BNs (stats fused into GEMM epilogues, bnfinal inlined in consumers)
  k_gemm1<<<(NN + 127) / 128, 512, 0, stream>>>(result, W1, t1, sums1, sumsq1);
  k_gemm2<<<(NN + 127) / 128, 512, 0, stream>>>(t1, W2, sums1, sumsq1, bn1_g, bn1_b,
                                                t2, sums2, sumsq2);
  k_colstats3<<<512, 256, 0, stream>>>(t2, sums2, sumsq2, bn2_g, bn2_b, sums3, sumsq3);
  k_final<<<NN * D / 4 / 256, 256, 0, stream>>>(t2, sums2, sumsq2, bn2_g, bn2_b,
                                                sums3, sumsq3, bn3_g, bn3_b);
}

// Round 5
// 877.104 us; speedup vs baseline: 3.4382x; 1.0069x over previous
//
#include <hip/hip_runtime.h>
#include <cstdint>
#include <cstddef>

#define NN 100000
#define D 128
#define NE 800000
#define BN_EPS 1e-5f

#define M4 (4 * NN)     // total buckets (dst-major: dst*4 + hop)
#define CH 1000         // scan chunk (buckets) = 250 pcount dwords
#define NB 400          // M4 / CH
#define G64 1563        // ceil(NN/64) row-blocks for MFMA gemms

typedef __attribute__((ext_vector_type(4))) float f32x4;
typedef __attribute__((ext_vector_type(8))) short s16x8;   // 8 bf16 in 4 VGPRs

__device__ inline unsigned short f2bf(float f) {           // RNE float->bf16
  unsigned int u = __builtin_bit_cast(unsigned int, f);
  u += 0x7FFFu + ((u >> 16) & 1u);
  return (unsigned short)(u >> 16);
}

// ---------------------------------------------------------------------------
// weight prep: W1[128][256] -> W1T bf16 [256][128]; W2[256][128] -> W2T bf16 [128][256]
__global__ __launch_bounds__(256) void k_prep(const float* __restrict__ W1,
                                              const float* __restrict__ W2,
                                              unsigned short* __restrict__ W1T,
                                              unsigned short* __restrict__ W2T) {
  int i = blockIdx.x * 256 + threadIdx.x;                  // grid 128 -> 32768
  if (i >= 32768) return;
  int k1 = i >> 8, n1 = i & 255;                           // W1[k1][n1]
  W1T[n1 * 128 + k1] = f2bf(W1[i]);
  int k2 = i >> 7, n2 = i & 127;                           // W2[k2][n2]
  W2T[n2 * 256 + k2] = f2bf(W2[i]);
}

// ---------------------------------------------------------------------------
// CSR build: packed per-dst counts (4 x u8 fields, one per hop); the atomic's
// return value IS the within-bucket rank -> no atomics needed in placement.
__global__ __launch_bounds__(256) void k_count(
    const int* __restrict__ e0, const int* __restrict__ e1,
    const int* __restrict__ e2, const int* __restrict__ e3,
    unsigned int* __restrict__ pcount, unsigned char* __restrict__ wrank) {
  const int h = blockIdx.y;
  const int* e = h == 0 ? e0 : h == 1 ? e1 : h == 2 ? e2 : e3;
  const int eid = blockIdx.x * 256 + threadIdx.x;   // grid.x = NE/256 exact
  const int dst = e[NE + eid];
  unsigned int old = atomicAdd(&pcount[dst], 1u << (8 * h));
  wrank[h * NE + eid] = (unsigned char)((old >> (8 * h)) & 0xFFu);
}

// chunk sums over packed counts (250 dwords = 1000 buckets per chunk)
__global__ __launch_bounds__(256) void k_scanA(const unsigned int* __restrict__ pcount,
                                               int* __restrict__ bsum) {
  __shared__ int red[256];
  const int b = blockIdx.x, t = threadIdx.x;
  int s = 0;
  if (t < 250) {
    unsigned int p = pcount[b * 250 + t];
    s = (int)((p & 0xFFu) + ((p >> 8) & 0xFFu) + ((p >> 16) & 0xFFu) + (p >> 24));
  }
  red[t] = s; __syncthreads();
  for (int off = 128; off > 0; off >>= 1) {
    if (t < off) red[t] += red[t + off];
    __syncthreads();
  }
  if (t == 0) bsum[b] = red[0];
}

// exclusive scan of chunk sums (NB=400 <= 512)
__global__ __launch_bounds__(512) void k_scanB(const int* __restrict__ bsum,
                                               int* __restrict__ bpre) {
  __shared__ int s[512];
  const int t = threadIdx.x;
  const int v = (t < NB) ? bsum[t] : 0;
  s[t] = v; __syncthreads();
  for (int off = 1; off < 512; off <<= 1) {
    int x = s[t];
    if (t >= off) x += s[t - off];
    __syncthreads(); s[t] = x; __syncthreads();
  }
  if (t < NB) bpre[t] = s[t] - v;
}

// per-chunk exclusive scan -> offsets
__global__ __launch_bounds__(256) void k_scanC(const unsigned int* __restrict__ pcount,
                                               const int* __restrict__ bpre,
                                               int* __restrict__ offsets) {
  __shared__ int cnt[CH];
  __shared__ int part[256];
  const int b = blockIdx.x, t = threadIdx.x;
  if (t < 250) {
    unsigned int p = pcount[b * 250 + t];
    cnt[t * 4 + 0] = (int)(p & 0xFFu);
    cnt[t * 4 + 1] = (int)((p >> 8) & 0xFFu);
    cnt[t * 4 + 2] = (int)((p >> 16) & 0xFFu);
    cnt[t * 4 + 3] = (int)(p >> 24);
  }
  __syncthreads();
  int own = 0;
#pragma unroll
  for (int j = 0; j < 4; j++) {
    int idx = t * 4 + j;
    if (idx < CH) own += cnt[idx];
  }
  part[t] = own; __syncthreads();
  for (int off = 1; off < 256; off <<= 1) {        // inclusive scan
    int x = part[t];
    if (t >= off) x += part[t - off];
    __syncthreads(); part[t] = x; __syncthreads();
  }
  int run = bpre[b] + part[t] - own;               // exclusive within chunk
#pragma unroll
  for (int j = 0; j < 4; j++) {
    int idx = t * 4 + j;
    if (idx < CH) { offsets[b * CH + idx] = run; run += cnt[idx]; }
  }
  if (b == 0 && t == 0) offsets[M4] = 4 * NE;
}

// placement: atomic-free (rank precomputed)
__global__ __launch_bounds__(256) void k_place(
    const int* __restrict__ e0, const int* __restrict__ e1,
    const int* __restrict__ e2, const int* __restrict__ e3,
    const int* __restrict__ offsets, const unsigned char* __restrict__ wrank,
    int* __restrict__ srcs, int* __restrict__ eids) {
  const int h = blockIdx.y;
  const int* e = h == 0 ? e0 : h == 1 ? e1 : h == 2 ? e2 : e3;
  const int eid = blockIdx.x * 256 + threadIdx.x;
  const int src = e[eid];
  const int dst = e[NE + eid];
  const int pos = offsets[dst * 4 + h] + (int)wrank[h * NE + eid];
  srcs[pos] = src;
  if (h == 0) eids[pos] = eid;
}

// ---------------------------------------------------------------------------
// One wave per dst node; 4 select-free hop loops; result emitted in bf16.
__global__ __launch_bounds__(256) void k_gather(
    const float* __restrict__ x0, const float* __restrict__ x1,
    const float* __restrict__ x2, const float* __restrict__ x3,
    const float* __restrict__ edge_attr, const float* __restrict__ eps,
    const int* __restrict__ offsets, const int* __restrict__ srcs,
    const int* __restrict__ eids, unsigned short* __restrict__ result) {
  const int dst  = blockIdx.x * 4 + (threadIdx.x >> 6);   // grid.x = NN/4 exact
  const int lane = threadIdx.x & 63;
  const int d    = lane * 2;

  const int4 ob = *reinterpret_cast<const int4*>(offsets + 4 * dst);
  const int o0 = ob.x, b1 = ob.y, b2 = ob.z, b3 = ob.w;
  const int o4 = offsets[4 * dst + 4];

  float2 h0 = make_float2(0.f, 0.f);
  float2 h1 = make_float2(0.f, 0.f);
  float2 h2 = make_float2(0.f, 0.f);
  float2 h3 = make_float2(0.f, 0.f);

  // ---- hop 0: x0[src] + edge_attr[eid]
  {
    int j = o0;
    for (; j + 2 <= b1; j += 2) {
      const int p0 = srcs[j],     p1 = srcs[j + 1];
      const int q0 = eids[j],     q1 = eids[j + 1];
      float2 v0 = *reinterpret_cast<const float2*>(x0 + p0 * D + d);
      float2 w0 = *reinterpret_cast<const float2*>(edge_attr + (size_t)q0 * D + d);
      float2 v1 = *reinterpret_cast<const float2*>(x0 + p1 * D + d);
      float2 w1 = *reinterpret_cast<const float2*>(edge_attr + (size_t)q1 * D + d);
      h0.x += fmaxf(v0.x + w0.x, 0.f); h0.y += fmaxf(v0.y + w0.y, 0.f);
      h0.x += fmaxf(v1.x + w1.x, 0.f); h0.y += fmaxf(v1.y + w1.y, 0.f);
    }
    if (j < b1) {
      const int p = srcs[j];
      const int q = eids[j];
      float2 v = *reinterpret_cast<const float2*>(x0 + p * D + d);
      float2 w = *reinterpret_cast<const float2*>(edge_attr + (size_t)q * D + d);
      h0.x += fmaxf(v.x + w.x, 0.f); h0.y += fmaxf(v.y + w.y, 0.f);
    }
  }

#define HOP_LOOP(XP, ACC, BEG, END) do {                                       \
    int j_ = (BEG);                                                            \
    for (; j_ + 4 <= (END); j_ += 4) {                                         \
      const int p0_ = srcs[j_], p1_ = srcs[j_ + 1];                            \
      const int p2_ = srcs[j_ + 2], p3_ = srcs[j_ + 3];                        \
      float2 v0_ = *reinterpret_cast<const float2*>((XP) + p0_ * D + d);       \
      float2 v1_ = *reinterpret_cast<const float2*>((XP) + p1_ * D + d);       \
      float2 v2_ = *reinterpret_cast<const float2*>((XP) + p2_ * D + d);       \
      float2 v3_ = *reinterpret_cast<const float2*>((XP) + p3_ * D + d);       \
      ACC.x += fmaxf(v0_.x, 0.f); ACC.y += fmaxf(v0_.y, 0.f);                  \
      ACC.x += fmaxf(v1_.x, 0.f); ACC.y += fmaxf(v1_.y, 0.f);                  \
      ACC.x += fmaxf(v2_.x, 0.f); ACC.y += fmaxf(v2_.y, 0.f);                  \
      ACC.x += fmaxf(v3_.x, 0.f); ACC.y += fmaxf(v3_.y, 0.f);                  \
    }                                                                          \
    for (; j_ < (END); ++j_) {                                                 \
      const int p_ = srcs[j_];                                                 \
      float2 v_ = *reinterpret_cast<const float2*>((XP) + p_ * D + d);         \
      ACC.x += fmaxf(v_.x, 0.f); ACC.y += fmaxf(v_.y, 0.f);                    \
    }                                                                          \
  } while (0)

  HOP_LOOP(x1, h1, b1, b2);
  HOP_LOOP(x2, h2, b2, b3);
  HOP_LOOP(x3, h3, b3, o4);
#undef HOP_LOOP

  float2 e0v = *reinterpret_cast<const float2*>(eps + d);
  float2 s1 = *reinterpret_cast<const float2*>(eps + 1 * D + d);
  float2 s2 = *reinterpret_cast<const float2*>(eps + 2 * D + d);
  float2 s3 = *reinterpret_cast<const float2*>(eps + 3 * D + d);
  float2 s4 = *reinterpret_cast<const float2*>(eps + 4 * D + d);
  float2 xv = *reinterpret_cast<const float2*>(x0 + dst * D + d);

  float ax = (1.f + e0v.x) * xv.x + (1.f + s1.x) * h0.x + (1.f + s2.x) * h1.x
           + (1.f + s3.x) * h2.x + (1.f + s4.x) * h3.x;
  float ay = (1.f + e0v.y) * xv.y + (1.f + s1.y) * h0.y + (1.f + s2.y) * h1.y
           + (1.f + s3.y) * h2.y + (1.f + s4.y) * h3.y;

  reinterpret_cast<unsigned int*>(result)[dst * 64 + lane] =
      (unsigned int)f2bf(ax) | ((unsigned int)f2bf(ay) << 16);
}

// ---------------------------------------------------------------------------
// GEMM1 (MFMA): t1[N,256] = Ab[N,128]bf16 @ W1T^T   (b1 cancels in BN1)
// 4 waves/block, wave = 16 rows x 256 cols; 64 mfma_f32_16x16x32_bf16 per wave.
__global__ __launch_bounds__(256) void k_gemm1(const unsigned short* __restrict__ Ab,
                                               const unsigned short* __restrict__ W1T,
                                               float* __restrict__ C) {
  const int lane = threadIdx.x & 63, wave = threadIdx.x >> 6;
  const int ln = lane & 15, lk = lane >> 4;
  const int m0 = blockIdx.x * 64 + wave * 16;
  const int arow = m0 + ln;
  const bool av = arow < NN;

  f32x4 acc[16];
#pragma unroll
  for (int t = 0; t < 16; t++) acc[t] = (f32x4)0.f;

#pragma unroll
  for (int kk = 0; kk < 4; kk++) {
    const int kb = kk * 32 + lk * 8;
    s16x8 a = (s16x8)(short)0;
    if (av) a = *reinterpret_cast<const s16x8*>(Ab + arow * 128 + kb);
#pragma unroll
    for (int t = 0; t < 16; t++) {
      s16x8 b = *reinterpret_cast<const s16x8*>(W1T + (t * 16 + ln) * 128 + kb);
      acc[t] = __builtin_amdgcn_mfma_f32_16x16x32_bf16(a, b, acc[t], 0, 0, 0);
    }
  }
#pragma unroll
  for (int t = 0; t < 16; t++) {
#pragma unroll
    for (int r = 0; r < 4; r++) {
      const int row = m0 + lk * 4 + r;
      if (row < NN) C[(size_t)row * 256 + t * 16 + ln] = acc[t][r];
    }
  }
}

// ---------------------------------------------------------------------------
// GEMM2 (MFMA): t2[N,128] = relu(bn1(t1))bf16 @ W2T^T  (b2 cancels in BN2)
__global__ __launch_bounds__(256) void k_gemm2(const float* __restrict__ t1,
                                               const unsigned short* __restrict__ W2T,
                                               const float* __restrict__ sc,
                                               const float* __restrict__ sh,
                                               float* __restrict__ C) {
  __shared__ float s1s[256], s1h[256];
  const int tid = threadIdx.x;
  if (tid < 256) { s1s[tid] = sc[tid]; s1h[tid] = sh[tid]; }
  __syncthreads();

  const int lane = tid & 63, wave = tid >> 6;
  const int ln = lane & 15, lk = lane >> 4;
  const int m0 = blockIdx.x * 64 + wave * 16;
  const int arow = m0 + ln;
  const bool av = arow < NN;

  f32x4 acc[8];
#pragma unroll
  for (int t = 0; t < 8; t++) acc[t] = (f32x4)0.f;

#pragma unroll
  for (int kk = 0; kk < 8; kk++) {
    const int kb = kk * 32 + lk * 8;
    float va[8];
    if (av) {
      *reinterpret_cast<float4*>(va)     = *reinterpret_cast<const float4*>(t1 + (size_t)arow * 256 + kb);
      *reinterpret_cast<float4*>(va + 4) = *reinterpret_cast<const float4*>(t1 + (size_t)arow * 256 + kb + 4);
    } else {
#pragma unroll
      for (int i = 0; i < 8; i++) va[i] = 0.f;
    }
    s16x8 a;
#pragma unroll
    for (int i = 0; i < 8; i++) {
      float v = fmaxf(fmaf(s1s[kb + i], va[i], s1h[kb + i]), 0.f);
      a[i] = (short)f2bf(v);
    }
#pragma unroll
    for (int t = 0; t < 8; t++) {
      s16x8 b = *reinterpret_cast<const s16x8*>(W2T + (t * 16 + ln) * 256 + kb);
      acc[t] = __builtin_amdgcn_mfma_f32_16x16x32_bf16(a, b, acc[t], 0, 0, 0);
    }
  }
#pragma unroll
  for (int t = 0; t < 8; t++) {
#pragma unroll
    for (int r = 0; r < 4; r++) {
      const int row = m0 + lk * 4 + r;
      if (row < NN) C[(size_t)row * 128 + t * 16 + ln] = acc[t][r];
    }
  }
}

// ---------------------------------------------------------------------------
template <int C, bool ACT>
__global__ __launch_bounds__(256) void k_colstats(const float* __restrict__ X,
                                                  const float* __restrict__ sc,
                                                  const float* __restrict__ sh,
                                                  float* __restrict__ sums,
                                                  float* __restrict__ sumsq) {
  const long total = (long)NN * C;
  const long stride = (long)gridDim.x * 256;
  const long start = (long)blockIdx.x * 256 + threadIdx.x;
  const int c = (int)(start & (C - 1));
  float scale = 0.f, shiftv = 0.f;
  if constexpr (ACT) { scale = sc[c]; shiftv = sh[c]; }
  float s = 0.f, q = 0.f;
  for (long idx = start; idx < total; idx += stride) {
    float v = X[idx];
    if constexpr (ACT) v = fmaxf(fmaf(scale, v, shiftv), 0.f);
    s += v;
    q = fmaf(v, v, q);
  }
  unsafeAtomicAdd(&sums[c], s);
  unsafeAtomicAdd(&sumsq[c], q);
}

template <int C>
__global__ void k_bnfinal(const float* __restrict__ sums, const float* __restrict__ sumsq,
                          const float* __restrict__ g, const float* __restrict__ b,
                          float* __restrict__ scale, float* __restrict__ shift) {
  int c = threadIdx.x;
  if (c >= C) return;
  float mean = sums[c] * (1.f / NN);
  float var  = sumsq[c] * (1.f / NN) - mean * mean;
  float rs   = rsqrtf(var + BN_EPS);
  float s    = g[c] * rs;
  scale[c] = s;
  shift[c] = b[c] - mean * s;
}

// ---------------------------------------------------------------------------
// Column stats of relu(bn2(t2)) -> sums3/sumsq3. BN2 scale/shift inlined.
__global__ __launch_bounds__(256) void k_colstats3(const float* __restrict__ X,
                                                   const float* __restrict__ sums2,
                                                   const float* __restrict__ sumsq2,
                                                   const float* __restrict__ bn2_g,
                                                   const float* __restrict__ bn2_b,
                                                   float* __restrict__ sums3,
                                                   float* __restrict__ sumsq3) {
  const long total = (long)NN * 128;
  const long stride = (long)gridDim.x * 256;
  const long start = (long)blockIdx.x * 256 + threadIdx.x;
  const int c = (int)(start & 127);
  float mean = sums2[c] * (1.f / NN);
  float var  = sumsq2[c] * (1.f / NN) - mean * mean;
  float rs   = rsqrtf(var + BN_EPS);
  float scale = bn2_g[c] * rs;
  float shiftv = bn2_b[c] - mean * scale;
  float s = 0.f, q = 0.f;
  for (long idx = start; idx < total; idx += stride) {
    float v = fmaxf(fmaf(scale, X[idx], shiftv), 0.f);
    s += v;
    q = fmaf(v, v, q);
  }
  unsafeAtomicAdd(&sums3[c], s);
  unsafeAtomicAdd(&sumsq3[c], q);
}

// out = relu(bn3(relu(bn2(t2)))), in place on d_out; BN2/BN3 inlined.
__global__ __launch_bounds__(256) void k_final(float* __restrict__ t2,
                                               const float* __restrict__ sums2,
                                               const float* __restrict__ sumsq2,
                                               const float* __restrict__ bn2_g,
                                               const float* __restrict__ bn2_b,
                                               const float* __restrict__ sums3,
                                               const float* __restrict__ sumsq3,
                                               const float* __restrict__ bn3_g,
                                               const float* __restrict__ bn3_b) {
  int i4 = blockIdx.x * 256 + threadIdx.x;
  if (i4 >= NN * D / 4) return;
  int d = (i4 & 31) * 4;
  float4 v = reinterpret_cast<float4*>(t2)[i4];
  float o[4];
  float* vv = reinterpret_cast<float*>(&v);
#pragma unroll
  for (int j = 0; j < 4; j++) {
    int c = d + j;
    float m2 = sums2[c] * (1.f / NN);
    float va2 = sumsq2[c] * (1.f / NN) - m2 * m2;
    float r2 = rsqrtf(va2 + BN_EPS);
    float a2 = bn2_g[c] * r2;
    float h2 = bn2_b[c] - m2 * a2;
    float m3 = sums3[c] * (1.f / NN);
    float va3 = sumsq3[c] * (1.f / NN) - m3 * m3;
    float r3 = rsqrtf(va3 + BN_EPS);
    float a3 = bn3_g[c] * r3;
    float h3 = bn3_b[c] - m3 * a3;
    o[j] = fmaxf(fmaf(a3, fmaxf(fmaf(a2, vv[j], h2), 0.f), h3), 0.f);
  }
  reinterpret_cast<float4*>(t2)[i4] = make_float4(o[0], o[1], o[2], o[3]);
}

// ---------------------------------------------------------------------------
extern "C" void kernel_launch(void* const* d_in, const int* in_sizes, int n_in,
                              void* d_out, int out_size, void* d_ws, size_t ws_size,
                              hipStream_t stream) {
  const float* x0 = (const float*)d_in[0];
  const float* x1 = (const float*)d_in[1];
  const float* x2 = (const float*)d_in[2];
  const float* x3 = (const float*)d_in[3];
  const float* edge_attr = (const float*)d_in[4];
  const int* e0 = (const int*)d_in[5];
  const int* e1 = (const int*)d_in[6];
  const int* e2 = (const int*)d_in[7];
  const int* e3 = (const int*)d_in[8];
  const float* W1 = (const float*)d_in[9];
  // d_in[10] = b1 (cancels in BN1)
  const float* bn1_g = (const float*)d_in[11];
  const float* bn1_b = (const float*)d_in[12];
  const float* W2 = (const float*)d_in[13];
  // d_in[14] = b2 (cancels in BN2)
  const float* bn2_g = (const float*)d_in[15];
  const float* bn2_b = (const float*)d_in[16];
  const float* bn3_g = (const float*)d_in[17];
  const float* bn3_b = (const float*)d_in[18];
  const float* eps = (const float*)d_in[19];

  char* ws = (char*)d_ws;
  unsigned short* resultb = (unsigned short*)ws;          // N*128 bf16 = 25.6MB
  float* t1 = (float*)(ws + (size_t)NN * D * 2);          // N*256 fp32 = 102.4MB
  float* stats = t1 + (size_t)NN * 256;
  float* sums1  = stats;           // 256
  float* sumsq1 = sums1 + 256;     // 256
  float* sums2  = sumsq1 + 256;    // 128
  float* sumsq2 = sums2 + 128;     // 128
  float* sums3  = sumsq2 + 128;    // 128
  float* sumsq3 = sums3 + 128;     // 128
  float* scale1 = sumsq3 + 128;    // 256
  float* shift1 = scale1 + 256;    // 256
  unsigned short* W1T = (unsigned short*)(shift1 + 256);  // 32768 bf16
  unsigned short* W2T = W1T + 32768;                      // 32768 bf16
  unsigned int* pcount = (unsigned int*)(W2T + 32768);    // NN packed counts
  unsigned char* wrank = (unsigned char*)(pcount + NN);   // 4*NE bytes

  // CSR arrays alias the t1 region (dead until k_gemm1 writes t1)
  int* offsets = (int*)t1;                          // M4+1
  int* bsum    = offsets + M4 + 1;                  // 400
  int* bpre    = bsum + NB;                         // 400
  int* srcs    = bpre + NB;                         // 3200000
  int* eids    = srcs + 4 * NE;                     // 3200000 (hop-0 region valid)

  float* t2 = (float*)d_out;                        // reuse output as t2

  hipMemsetAsync(pcount, 0, NN * sizeof(unsigned int), stream);
  hipMemsetAsync(stats, 0, 1024 * sizeof(float), stream);

  k_prep<<<128, 256, 0, stream>>>(W1, W2, W1T, W2T);

  // CSR build (packed counts; rank returned by the counting atomic)
  k_count<<<dim3(NE / 256, 4), 256, 0, stream>>>(e0, e1, e2, e3, pcount, wrank);
  k_scanA<<<NB, 256, 0, stream>>>(pcount, bsum);
  k_scanB<<<1, 512, 0, stream>>>(bsum, bpre);
  k_scanC<<<NB, 256, 0, stream>>>(pcount, bpre, offsets);
  k_place<<<dim3(NE / 256, 4), 256, 0, stream>>>(e0, e1, e2, e3, offsets, wrank, srcs, eids);

  // select-free per-hop loops, one wave per node; bf16 output
  k_gather<<<NN / 4, 256, 0, stream>>>(x0, x1, x2, x3, edge_attr, eps,
                                       offsets, srcs, eids, resultb);

  // MLP + BNs (MFMA GEMMs; stats as cheap grid-stride passes)
  k_gemm1<<<G64, 256, 0, stream>>>(resultb, W1T, t1);
  k_colstats<256, false><<<512, 256, 0, stream>>>(t1, nullptr, nullptr, sums1, sumsq1);
  k_bnfinal<256><<<1, 256, 0, stream>>>(sums1, sumsq1, bn1_g, bn1_b, scale1, shift1);
  k_gemm2<<<G64, 256, 0, stream>>>(t1, W2T, scale1, shift1, t2);
  k_colstats<128, false><<<512, 256, 0, stream>>>(t2, nullptr, nullptr, sums2, sumsq2);
  k_colstats3<<<512, 256, 0, stream>>>(t2, sums2, sumsq2, bn2_g, bn2_b, sums3, sumsq3);
  k_final<<<NN * D / 4 / 256, 256, 0, stream>>>(t2, sums2, sumsq2, bn2_g, bn2_b,
                                                sums3, sumsq3, bn3_g, bn3_b);
}

// Round 6
// 861.664 us; speedup vs baseline: 3.4998x; 1.0179x over previous
//
#include <hip/hip_runtime.h>
#include <cstdint>
#include <cstddef>

#define NN 100000
#define D 128
#define NE 800000
#define BN_EPS 1e-5f

#define M4 (4 * NN)     // total buckets (dst-major: dst*4 + hop)
#define CH 1000         // scan chunk (buckets) = 250 pcount dwords
#define NB 400          // M4 / CH
#define GB 782          // ceil(NN/128) row-blocks for MFMA gemms

typedef __attribute__((ext_vector_type(4))) float f32x4;
typedef __attribute__((ext_vector_type(2))) float f32x2;
typedef __attribute__((ext_vector_type(8))) short s16x8;   // 8 bf16 in 4 VGPRs

__device__ inline unsigned short f2bf(float f) {           // RNE float->bf16
  unsigned int u = __builtin_bit_cast(unsigned int, f);
  u += 0x7FFFu + ((u >> 16) & 1u);
  return (unsigned short)(u >> 16);
}
__device__ inline float bf2f(unsigned short u) {
  unsigned int x = ((unsigned int)u) << 16;
  return __builtin_bit_cast(float, x);
}
__device__ inline f32x2 ntload2(const float* p) {          // streaming load
  return __builtin_nontemporal_load(reinterpret_cast<const f32x2*>(p));
}

// ---------------------------------------------------------------------------
// weight prep: W1[128][256] -> W1T bf16 [256][128]; W2[256][128] -> W2T bf16 [128][256]
__global__ __launch_bounds__(256) void k_prep(const float* __restrict__ W1,
                                              const float* __restrict__ W2,
                                              unsigned short* __restrict__ W1T,
                                              unsigned short* __restrict__ W2T) {
  int i = blockIdx.x * 256 + threadIdx.x;                  // grid 128 -> 32768
  if (i >= 32768) return;
  int k1 = i >> 8, n1 = i & 255;                           // W1[k1][n1]
  W1T[n1 * 128 + k1] = f2bf(W1[i]);
  int k2 = i >> 7, n2 = i & 127;                           // W2[k2][n2]
  W2T[n2 * 256 + k2] = f2bf(W2[i]);
}

// ---------------------------------------------------------------------------
// CSR build: packed per-dst counts (4 x u8 fields, one per hop); the atomic's
// return value IS the within-bucket rank -> no atomics in placement.
__global__ __launch_bounds__(256) void k_count(
    const int* __restrict__ e0, const int* __restrict__ e1,
    const int* __restrict__ e2, const int* __restrict__ e3,
    unsigned int* __restrict__ pcount, unsigned char* __restrict__ wrank) {
  const int h = blockIdx.y;
  const int* e = h == 0 ? e0 : h == 1 ? e1 : h == 2 ? e2 : e3;
  const int eid = blockIdx.x * 256 + threadIdx.x;   // grid.x = NE/256 exact
  const int dst = e[NE + eid];
  unsigned int old = atomicAdd(&pcount[dst], 1u << (8 * h));
  wrank[h * NE + eid] = (unsigned char)((old >> (8 * h)) & 0xFFu);
}

// chunk sums over packed counts (250 dwords = 1000 buckets per chunk)
__global__ __launch_bounds__(256) void k_scanA(const unsigned int* __restrict__ pcount,
                                               int* __restrict__ bsum) {
  __shared__ int red[256];
  const int b = blockIdx.x, t = threadIdx.x;
  int s = 0;
  if (t < 250) {
    unsigned int p = pcount[b * 250 + t];
    s = (int)((p & 0xFFu) + ((p >> 8) & 0xFFu) + ((p >> 16) & 0xFFu) + (p >> 24));
  }
  red[t] = s; __syncthreads();
  for (int off = 128; off > 0; off >>= 1) {
    if (t < off) red[t] += red[t + off];
    __syncthreads();
  }
  if (t == 0) bsum[b] = red[0];
}

// exclusive scan of chunk sums (NB=400 <= 512)
__global__ __launch_bounds__(512) void k_scanB(const int* __restrict__ bsum,
                                               int* __restrict__ bpre) {
  __shared__ int s[512];
  const int t = threadIdx.x;
  const int v = (t < NB) ? bsum[t] : 0;
  s[t] = v; __syncthreads();
  for (int off = 1; off < 512; off <<= 1) {
    int x = s[t];
    if (t >= off) x += s[t - off];
    __syncthreads(); s[t] = x; __syncthreads();
  }
  if (t < NB) bpre[t] = s[t] - v;
}

// per-chunk exclusive scan -> offsets
__global__ __launch_bounds__(256) void k_scanC(const unsigned int* __restrict__ pcount,
                                               const int* __restrict__ bpre,
                                               int* __restrict__ offsets) {
  __shared__ int cnt[CH];
  __shared__ int part[256];
  const int b = blockIdx.x, t = threadIdx.x;
  if (t < 250) {
    unsigned int p = pcount[b * 250 + t];
    cnt[t * 4 + 0] = (int)(p & 0xFFu);
    cnt[t * 4 + 1] = (int)((p >> 8) & 0xFFu);
    cnt[t * 4 + 2] = (int)((p >> 16) & 0xFFu);
    cnt[t * 4 + 3] = (int)(p >> 24);
  }
  __syncthreads();
  int own = 0;
#pragma unroll
  for (int j = 0; j < 4; j++) {
    int idx = t * 4 + j;
    if (idx < CH) own += cnt[idx];
  }
  part[t] = own; __syncthreads();
  for (int off = 1; off < 256; off <<= 1) {        // inclusive scan
    int x = part[t];
    if (t >= off) x += part[t - off];
    __syncthreads(); part[t] = x; __syncthreads();
  }
  int run = bpre[b] + part[t] - own;               // exclusive within chunk
#pragma unroll
  for (int j = 0; j < 4; j++) {
    int idx = t * 4 + j;
    if (idx < CH) { offsets[b * CH + idx] = run; run += cnt[idx]; }
  }
  if (b == 0 && t == 0) offsets[M4] = 4 * NE;
}

// placement, atomic-free. hop0 stores eid only (src re-derived from e0 later).
__global__ __launch_bounds__(256) void k_place(
    const int* __restrict__ e0, const int* __restrict__ e1,
    const int* __restrict__ e2, const int* __restrict__ e3,
    const int* __restrict__ offsets, const unsigned char* __restrict__ wrank,
    int* __restrict__ srcs, int* __restrict__ eids) {
  const int h = blockIdx.y;
  const int* e = h == 0 ? e0 : h == 1 ? e1 : h == 2 ? e2 : e3;
  const int eid = blockIdx.x * 256 + threadIdx.x;
  const int dst = e[NE + eid];
  const int pos = offsets[dst * 4 + h] + (int)wrank[h * NE + eid];
  if (h == 0) {
    eids[pos] = eid;
  } else {
    srcs[pos] = e[eid];
  }
}

// ---------------------------------------------------------------------------
// One wave per dst node; 4 select-free hop loops; edge_attr via NT loads
// (one-touch 410MB stream must not evict the L3-resident x tables).
__global__ __launch_bounds__(256) void k_gather(
    const float* __restrict__ x0, const float* __restrict__ x1,
    const float* __restrict__ x2, const float* __restrict__ x3,
    const float* __restrict__ edge_attr, const float* __restrict__ eps,
    const int* __restrict__ e0, const int* __restrict__ offsets,
    const int* __restrict__ srcs, const int* __restrict__ eids,
    unsigned short* __restrict__ result) {
  const int dst  = blockIdx.x * 4 + (threadIdx.x >> 6);   // grid.x = NN/4 exact
  const int lane = threadIdx.x & 63;
  const int d    = lane * 2;

  const int4 ob = *reinterpret_cast<const int4*>(offsets + 4 * dst);
  const int o0 = ob.x, b1 = ob.y, b2 = ob.z, b3 = ob.w;
  const int o4 = offsets[4 * dst + 4];

  float2 h0 = make_float2(0.f, 0.f);
  float2 h1 = make_float2(0.f, 0.f);
  float2 h2 = make_float2(0.f, 0.f);
  float2 h3 = make_float2(0.f, 0.f);

  // ---- hop 0: relu(x0[e0[eid]] + edge_attr[eid]), unroll x4
  {
    int j = o0;
    for (; j + 4 <= b1; j += 4) {
      const int q0 = eids[j], q1 = eids[j + 1], q2 = eids[j + 2], q3 = eids[j + 3];
      const int p0 = e0[q0], p1 = e0[q1], p2 = e0[q2], p3 = e0[q3];
      f32x2 w0 = ntload2(edge_attr + (size_t)q0 * D + d);
      f32x2 w1 = ntload2(edge_attr + (size_t)q1 * D + d);
      f32x2 w2 = ntload2(edge_attr + (size_t)q2 * D + d);
      f32x2 w3 = ntload2(edge_attr + (size_t)q3 * D + d);
      float2 v0 = *reinterpret_cast<const float2*>(x0 + p0 * D + d);
      float2 v1 = *reinterpret_cast<const float2*>(x0 + p1 * D + d);
      float2 v2 = *reinterpret_cast<const float2*>(x0 + p2 * D + d);
      float2 v3 = *reinterpret_cast<const float2*>(x0 + p3 * D + d);
      h0.x += fmaxf(v0.x + w0[0], 0.f); h0.y += fmaxf(v0.y + w0[1], 0.f);
      h0.x += fmaxf(v1.x + w1[0], 0.f); h0.y += fmaxf(v1.y + w1[1], 0.f);
      h0.x += fmaxf(v2.x + w2[0], 0.f); h0.y += fmaxf(v2.y + w2[1], 0.f);
      h0.x += fmaxf(v3.x + w3[0], 0.f); h0.y += fmaxf(v3.y + w3[1], 0.f);
    }
    for (; j < b1; ++j) {
      const int q = eids[j];
      const int p = e0[q];
      f32x2 w = ntload2(edge_attr + (size_t)q * D + d);
      float2 v = *reinterpret_cast<const float2*>(x0 + p * D + d);
      h0.x += fmaxf(v.x + w[0], 0.f); h0.y += fmaxf(v.y + w[1], 0.f);
    }
  }

#define HOP_LOOP(XP, ACC, BEG, END) do {                                       \
    int j_ = (BEG);                                                            \
    for (; j_ + 4 <= (END); j_ += 4) {                                         \
      const int p0_ = srcs[j_], p1_ = srcs[j_ + 1];                            \
      const int p2_ = srcs[j_ + 2], p3_ = srcs[j_ + 3];                        \
      float2 v0_ = *reinterpret_cast<const float2*>((XP) + p0_ * D + d);       \
      float2 v1_ = *reinterpret_cast<const float2*>((XP) + p1_ * D + d);       \
      float2 v2_ = *reinterpret_cast<const float2*>((XP) + p2_ * D + d);       \
      float2 v3_ = *reinterpret_cast<const float2*>((XP) + p3_ * D + d);       \
      ACC.x += fmaxf(v0_.x, 0.f); ACC.y += fmaxf(v0_.y, 0.f);                  \
      ACC.x += fmaxf(v1_.x, 0.f); ACC.y += fmaxf(v1_.y, 0.f);                  \
      ACC.x += fmaxf(v2_.x, 0.f); ACC.y += fmaxf(v2_.y, 0.f);                  \
      ACC.x += fmaxf(v3_.x, 0.f); ACC.y += fmaxf(v3_.y, 0.f);                  \
    }                                                                          \
    for (; j_ < (END); ++j_) {                                                 \
      const int p_ = srcs[j_];                                                 \
      float2 v_ = *reinterpret_cast<const float2*>((XP) + p_ * D + d);         \
      ACC.x += fmaxf(v_.x, 0.f); ACC.y += fmaxf(v_.y, 0.f);                    \
    }                                                                          \
  } while (0)

  HOP_LOOP(x1, h1, b1, b2);
  HOP_LOOP(x2, h2, b2, b3);
  HOP_LOOP(x3, h3, b3, o4);
#undef HOP_LOOP

  float2 e0v = *reinterpret_cast<const float2*>(eps + d);
  float2 s1 = *reinterpret_cast<const float2*>(eps + 1 * D + d);
  float2 s2 = *reinterpret_cast<const float2*>(eps + 2 * D + d);
  float2 s3 = *reinterpret_cast<const float2*>(eps + 3 * D + d);
  float2 s4 = *reinterpret_cast<const float2*>(eps + 4 * D + d);
  float2 xv = *reinterpret_cast<const float2*>(x0 + dst * D + d);

  float ax = (1.f + e0v.x) * xv.x + (1.f + s1.x) * h0.x + (1.f + s2.x) * h1.x
           + (1.f + s3.x) * h2.x + (1.f + s4.x) * h3.x;
  float ay = (1.f + e0v.y) * xv.y + (1.f + s1.y) * h0.y + (1.f + s2.y) * h1.y
           + (1.f + s3.y) * h2.y + (1.f + s4.y) * h3.y;

  reinterpret_cast<unsigned int*>(result)[dst * 64 + lane] =
      (unsigned int)f2bf(ax) | ((unsigned int)f2bf(ay) << 16);
}

// ---------------------------------------------------------------------------
// GEMM1 (MFMA): t1b[N,256]bf16 = Ab[N,128]bf16 @ W1T^T  (b1 cancels in BN1)
// 8 waves x 16 rows = 128 rows/block. Fused BN1 stats from fp32 accs.
__global__ __launch_bounds__(512) void k_gemm1(const unsigned short* __restrict__ Ab,
                                               const unsigned short* __restrict__ W1T,
                                               unsigned short* __restrict__ t1b,
                                               float* __restrict__ sums1,
                                               float* __restrict__ sumsq1) {
  __shared__ float ls[256], lq[256];
  const int tid = threadIdx.x;
  if (tid < 256) { ls[tid] = 0.f; lq[tid] = 0.f; }
  __syncthreads();

  const int lane = tid & 63, wave = tid >> 6;
  const int ln = lane & 15, lk = lane >> 4;
  const int m0 = blockIdx.x * 128 + wave * 16;
  const int arow = m0 + ln;
  const bool av = arow < NN;

  f32x4 acc[16];
#pragma unroll
  for (int t = 0; t < 16; t++) acc[t] = (f32x4)0.f;

#pragma unroll
  for (int kk = 0; kk < 4; kk++) {
    const int kb = kk * 32 + lk * 8;
    s16x8 a = (s16x8)(short)0;
    if (av) a = *reinterpret_cast<const s16x8*>(Ab + arow * 128 + kb);
#pragma unroll
    for (int t = 0; t < 16; t++) {
      s16x8 b = *reinterpret_cast<const s16x8*>(W1T + (t * 16 + ln) * 128 + kb);
      acc[t] = __builtin_amdgcn_mfma_f32_16x16x32_bf16(a, b, acc[t], 0, 0, 0);
    }
  }
#pragma unroll
  for (int t = 0; t < 16; t++) {
    float cs = 0.f, cq = 0.f;
#pragma unroll
    for (int r = 0; r < 4; r++) {
      const int row = m0 + lk * 4 + r;
      float v = acc[t][r];
      if (row < NN) t1b[(size_t)row * 256 + t * 16 + ln] = f2bf(v);
      cs += v;                      // rows >= NN have acc == 0 (a zeroed)
      cq = fmaf(v, v, cq);
    }
    atomicAdd(&ls[t * 16 + ln], cs);
    atomicAdd(&lq[t * 16 + ln], cq);
  }
  __syncthreads();
  if (tid < 256) {
    unsafeAtomicAdd(&sums1[tid], ls[tid]);
    unsafeAtomicAdd(&sumsq1[tid], lq[tid]);
  }
}

// ---------------------------------------------------------------------------
// GEMM2 (MFMA): t2[N,128]fp32 = relu(bn1(t1b))bf16 @ W2T^T (b2 cancels in BN2)
// BN1 scale/shift computed inline from raw sums; fused BN2 stats.
__global__ __launch_bounds__(512) void k_gemm2(const unsigned short* __restrict__ t1b,
                                               const unsigned short* __restrict__ W2T,
                                               const float* __restrict__ sums1,
                                               const float* __restrict__ sumsq1,
                                               const float* __restrict__ bn1_g,
                                               const float* __restrict__ bn1_b,
                                               float* __restrict__ C,
                                               float* __restrict__ sums2,
                                               float* __restrict__ sumsq2) {
  __shared__ float s1s[256], s1h[256];
  __shared__ float ls[128], lq[128];
  const int tid = threadIdx.x;
  if (tid < 256) {
    float mean = sums1[tid] * (1.f / NN);
    float var  = sumsq1[tid] * (1.f / NN) - mean * mean;
    float rs   = rsqrtf(var + BN_EPS);
    float s    = bn1_g[tid] * rs;
    s1s[tid] = s;
    s1h[tid] = bn1_b[tid] - mean * s;
  }
  if (tid < 128) { ls[tid] = 0.f; lq[tid] = 0.f; }
  __syncthreads();

  const int lane = tid & 63, wave = tid >> 6;
  const int ln = lane & 15, lk = lane >> 4;
  const int m0 = blockIdx.x * 128 + wave * 16;
  const int arow = m0 + ln;
  const bool av = arow < NN;

  f32x4 acc[8];
#pragma unroll
  for (int t = 0; t < 8; t++) acc[t] = (f32x4)0.f;

#pragma unroll
  for (int kk = 0; kk < 8; kk++) {
    const int kb = kk * 32 + lk * 8;
    s16x8 raw = (s16x8)(short)0;
    if (av) raw = *reinterpret_cast<const s16x8*>(t1b + (size_t)arow * 256 + kb);
    s16x8 a;
#pragma unroll
    for (int i = 0; i < 8; i++) {
      const int col = kb + i;
      float v = fmaxf(fmaf(s1s[col], bf2f((unsigned short)raw[i]), s1h[col]), 0.f);
      a[i] = (short)f2bf(av ? v : 0.f);
    }
#pragma unroll
    for (int t = 0; t < 8; t++) {
      s16x8 b = *reinterpret_cast<const s16x8*>(W2T + (t * 16 + ln) * 256 + kb);
      acc[t] = __builtin_amdgcn_mfma_f32_16x16x32_bf16(a, b, acc[t], 0, 0, 0);
    }
  }
#pragma unroll
  for (int t = 0; t < 8; t++) {
    float cs = 0.f, cq = 0.f;
#pragma unroll
    for (int r = 0; r < 4; r++) {
      const int row = m0 + lk * 4 + r;
      float v = acc[t][r];
      if (row < NN) {
        C[(size_t)row * 128 + t * 16 + ln] = v;
        cs += v;
        cq = fmaf(v, v, cq);
      }
    }
    atomicAdd(&ls[t * 16 + ln], cs);
    atomicAdd(&lq[t * 16 + ln], cq);
  }
  __syncthreads();
  if (tid < 128) {
    unsafeAtomicAdd(&sums2[tid], ls[tid]);
    unsafeAtomicAdd(&sumsq2[tid], lq[tid]);
  }
}

// ---------------------------------------------------------------------------
// Column stats of relu(bn2(t2)) -> sums3/sumsq3. BN2 scale/shift inlined.
__global__ __launch_bounds__(256) void k_colstats3(const float* __restrict__ X,
                                                   const float* __restrict__ sums2,
                                                   const float* __restrict__ sumsq2,
                                                   const float* __restrict__ bn2_g,
                                                   const float* __restrict__ bn2_b,
                                                   float* __restrict__ sums3,
                                                   float* __restrict__ sumsq3) {
  const long total = (long)NN * 128;
  const long stride = (long)gridDim.x * 256;
  const long start = (long)blockIdx.x * 256 + threadIdx.x;
  const int c = (int)(start & 127);
  float mean = sums2[c] * (1.f / NN);
  float var  = sumsq2[c] * (1.f / NN) - mean * mean;
  float rs   = rsqrtf(var + BN_EPS);
  float scale = bn2_g[c] * rs;
  float shiftv = bn2_b[c] - mean * scale;
  float s = 0.f, q = 0.f;
  for (long idx = start; idx < total; idx += stride) {
    float v = fmaxf(fmaf(scale, X[idx], shiftv), 0.f);
    s += v;
    q = fmaf(v, v, q);
  }
  unsafeAtomicAdd(&sums3[c], s);
  unsafeAtomicAdd(&sumsq3[c], q);
}

// out = relu(bn3(relu(bn2(t2)))), in place on d_out; BN2/BN3 inlined.
__global__ __launch_bounds__(256) void k_final(float* __restrict__ t2,
                                               const float* __restrict__ sums2,
                                               const float* __restrict__ sumsq2,
                                               const float* __restrict__ bn2_g,
                                               const float* __restrict__ bn2_b,
                                               const float* __restrict__ sums3,
                                               const float* __restrict__ sumsq3,
                                               const float* __restrict__ bn3_g,
                                               const float* __restrict__ bn3_b) {
  int i4 = blockIdx.x * 256 + threadIdx.x;
  if (i4 >= NN * D / 4) return;
  int d = (i4 & 31) * 4;
  float4 v = reinterpret_cast<float4*>(t2)[i4];
  float o[4];
  float* vv = reinterpret_cast<float*>(&v);
#pragma unroll
  for (int j = 0; j < 4; j++) {
    int c = d + j;
    float m2 = sums2[c] * (1.f / NN);
    float va2 = sumsq2[c] * (1.f / NN) - m2 * m2;
    float r2 = rsqrtf(va2 + BN_EPS);
    float a2 = bn2_g[c] * r2;
    float h2 = bn2_b[c] - m2 * a2;
    float m3 = sums3[c] * (1.f / NN);
    float va3 = sumsq3[c] * (1.f / NN) - m3 * m3;
    float r3 = rsqrtf(va3 + BN_EPS);
    float a3 = bn3_g[c] * r3;
    float h3 = bn3_b[c] - m3 * a3;
    o[j] = fmaxf(fmaf(a3, fmaxf(fmaf(a2, vv[j], h2), 0.f), h3), 0.f);
  }
  reinterpret_cast<float4*>(t2)[i4] = make_float4(o[0], o[1], o[2], o[3]);
}

// ---------------------------------------------------------------------------
extern "C" void kernel_launch(void* const* d_in, const int* in_sizes, int n_in,
                              void* d_out, int out_size, void* d_ws, size_t ws_size,
                              hipStream_t stream) {
  const float* x0 = (const float*)d_in[0];
  const float* x1 = (const float*)d_in[1];
  const float* x2 = (const float*)d_in[2];
  const float* x3 = (const float*)d_in[3];
  const float* edge_attr = (const float*)d_in[4];
  const int* e0 = (const int*)d_in[5];
  const int* e1 = (const int*)d_in[6];
  const int* e2 = (const int*)d_in[7];
  const int* e3 = (const int*)d_in[8];
  const float* W1 = (const float*)d_in[9];
  // d_in[10] = b1 (cancels in BN1)
  const float* bn1_g = (const float*)d_in[11];
  const float* bn1_b = (const float*)d_in[12];
  const float* W2 = (const float*)d_in[13];
  // d_in[14] = b2 (cancels in BN2)
  const float* bn2_g = (const float*)d_in[15];
  const float* bn2_b = (const float*)d_in[16];
  const float* bn3_g = (const float*)d_in[17];
  const float* bn3_b = (const float*)d_in[18];
  const float* eps = (const float*)d_in[19];

  char* ws = (char*)d_ws;
  unsigned short* resultb = (unsigned short*)ws;          // N*128 bf16 = 25.6MB
  unsigned short* t1b = (unsigned short*)(ws + (size_t)NN * D * 2);  // N*256 bf16 = 51.2MB
  float* stats = (float*)(ws + (size_t)NN * D * 2 + (size_t)NN * 256 * 2);
  float* sums1  = stats;           // 256
  float* sumsq1 = sums1 + 256;     // 256
  float* sums2  = sumsq1 + 256;    // 128
  float* sumsq2 = sums2 + 128;     // 128
  float* sums3  = sumsq2 + 128;    // 128
  float* sumsq3 = sums3 + 128;     // 128
  unsigned short* W1T = (unsigned short*)(sumsq3 + 128);  // 32768 bf16
  unsigned short* W2T = W1T + 32768;                      // 32768 bf16
  unsigned int* pcount = (unsigned int*)(W2T + 32768);    // NN packed counts
  unsigned char* wrank = (unsigned char*)(pcount + NN);   // 4*NE bytes

  // CSR arrays alias the t1b region (dead until k_gemm1 writes t1b)
  int* offsets = (int*)t1b;                         // M4+1
  int* bsum    = offsets + M4 + 1;                  // 400
  int* bpre    = bsum + NB;                         // 400
  int* srcs    = bpre + NB;                         // 4*NE (hops 1-3 valid)
  int* eids    = srcs + 4 * NE;                     // 4*NE (hop-0 region valid)

  float* t2 = (float*)d_out;                        // reuse output as t2

  hipMemsetAsync(pcount, 0, NN * sizeof(unsigned int), stream);
  hipMemsetAsync(stats, 0, 1024 * sizeof(float), stream);

  k_prep<<<128, 256, 0, stream>>>(W1, W2, W1T, W2T);

  // CSR build (packed counts; rank returned by the counting atomic)
  k_count<<<dim3(NE / 256, 4), 256, 0, stream>>>(e0, e1, e2, e3, pcount, wrank);
  k_scanA<<<NB, 256, 0, stream>>>(pcount, bsum);
  k_scanB<<<1, 512, 0, stream>>>(bsum, bpre);
  k_scanC<<<NB, 256, 0, stream>>>(pcount, bpre, offsets);
  k_place<<<dim3(NE / 256, 4), 256, 0, stream>>>(e0, e1, e2, e3, offsets, wrank, srcs, eids);

  // select-free per-hop loops, one wave per node; NT edge_attr; bf16 output
  k_gather<<<NN / 4, 256, 0, stream>>>(x0, x1, x2, x3, edge_attr, eps, e0,
                                       offsets, srcs, eids, resultb);

  // MLP + BNs (MFMA GEMMs with fused stats; bn params inlined in consumers)
  k_gemm1<<<GB, 512, 0, stream>>>(resultb, W1T, t1b, sums1, sumsq1);
  k_gemm2<<<GB, 512, 0, stream>>>(t1b, W2T, sums1, sumsq1, bn1_g, bn1_b,
                                  t2, sums2, sumsq2);
  k_colstats3<<<512, 256, 0, stream>>>(t2, sums2, sumsq2, bn2_g, bn2_b, sums3, sumsq3);
  k_final<<<NN * D / 4 / 256, 256, 0, stream>>>(t2, sums2, sumsq2, bn2_g, bn2_b,
                                                sums3, sumsq3, bn3_g, bn3_b);
}